// Round 2
// baseline (7095.498 us; speedup 1.0000x reference)
//
#include <hip/hip_runtime.h>
#include <hip/hip_bf16.h>
#include <math.h>

typedef __hip_bfloat16 bf16;

#define BATCH_N 4
#define SEQ_N 4096
#define DMODEL 1024
#define DINNER 2048
#define DTRANK 64
#define DSTATE 16
#define NROWS (BATCH_N * SEQ_N)   // 16384

__device__ __forceinline__ float b2f(bf16 v) { return __bfloat162float(v); }
__device__ __forceinline__ bf16 f2b(float v) { return __float2bfloat16(v); }

// ---------------- f32 -> bf16 convert (weights) ----------------
__global__ void f32_to_bf16_kernel(const float* __restrict__ in, bf16* __restrict__ out, int n) {
    int i = blockIdx.x * 256 + threadIdx.x;
    if (i < n) out[i] = f2b(in[i]);
}

// ---------------- RMSNorm scale per row: rscale[r] = rsqrt(mean(x_r^2)+eps) ----------------
__global__ __launch_bounds__(256) void rms_scale_kernel(const float* __restrict__ x,
                                                        float* __restrict__ scale) {
    const int r = blockIdx.x;
    const int t = threadIdx.x;
    const float4 v = reinterpret_cast<const float4*>(x + (size_t)r * DMODEL)[t];
    float ss = v.x * v.x + v.y * v.y + v.z * v.z + v.w * v.w;
    #pragma unroll
    for (int o = 32; o > 0; o >>= 1) ss += __shfl_down(ss, o);
    __shared__ float red[4];
    if ((t & 63) == 0) red[t >> 6] = ss;
    __syncthreads();
    if (t == 0) {
        const float tot = red[0] + red[1] + red[2] + red[3];
        scale[r] = rsqrtf(tot * (1.0f / DMODEL) + 1e-6f);
    }
}

// ---------------- causal depthwise conv (width 4) + silu ----------------
// xcraw: [NROWS, DINNER] bf16 -> xc: [NROWS, DINNER] bf16
__global__ __launch_bounds__(256) void conv_silu_kernel(const bf16* __restrict__ xcraw,
                                                        const float* __restrict__ cw,
                                                        const float* __restrict__ cb,
                                                        bf16* __restrict__ xc) {
    const int idx = blockIdx.x * 256 + threadIdx.x;       // (row, e)
    const int e = idx & (DINNER - 1);
    const int r = idx >> 11;
    const int l = r & (SEQ_N - 1);
    const float4 w = *reinterpret_cast<const float4*>(cw + e * 4);
    float xs[4];
    #pragma unroll
    for (int k = 0; k < 4; ++k) {
        const int lp = l - 3 + k;
        xs[k] = (lp >= 0) ? b2f(xcraw[(size_t)(r - 3 + k) * DINNER + e]) : 0.f;
    }
    const float acc = cb[e] + w.x * xs[0] + w.y * xs[1] + w.z * xs[2] + w.w * xs[3];
    xc[idx] = f2b(acc / (1.f + __expf(-acc)));
}

// ---------------- generic GEMM: C[M,N] = (ascale[m] *) A[M,K] @ B[N,K]^T (+ epilogue) ----------
// EPI 0: store acc. EPI 1: softplus(acc + aux[n]). EPI 2: acc + aux[m*ldc+n] (residual).
template <int EPI, typename AT, typename OT>
__global__ __launch_bounds__(256) void gemm_bt(const AT* __restrict__ A, int lda,
                                               const float* __restrict__ ascale,
                                               const bf16* __restrict__ B,
                                               OT* __restrict__ C, int ldc,
                                               const float* __restrict__ aux,
                                               int N, int K) {
    __shared__ float As[32][64];
    __shared__ float Bs[32][64];
    const int m0 = blockIdx.x * 64;
    const int n0 = blockIdx.y * 64;
    const int t = threadIdx.x;
    const int lr = t >> 2;          // 0..63
    const int lk = (t & 3) * 8;     // 0,8,16,24
    const int tx = (t & 15) * 4;
    const int ty = (t >> 4) * 4;
    const float s = ascale ? ascale[m0 + lr] : 1.0f;
    float acc[4][4] = {{0.f}};
    for (int k0 = 0; k0 < K; k0 += 32) {
        float av[8], bv[8];
        if constexpr (sizeof(AT) == 2) {
            union { uint4 u; bf16 h[8]; } tmp;
            tmp.u = *reinterpret_cast<const uint4*>(A + (size_t)(m0 + lr) * lda + k0 + lk);
            #pragma unroll
            for (int i = 0; i < 8; ++i) av[i] = b2f(tmp.h[i]);
        } else {
            const float4* p = reinterpret_cast<const float4*>(A + (size_t)(m0 + lr) * lda + k0 + lk);
            float4 a0 = p[0], a1 = p[1];
            av[0] = a0.x; av[1] = a0.y; av[2] = a0.z; av[3] = a0.w;
            av[4] = a1.x; av[5] = a1.y; av[6] = a1.z; av[7] = a1.w;
        }
        if (ascale) {
            #pragma unroll
            for (int i = 0; i < 8; ++i) av[i] *= s;
        }
        {
            const int n = n0 + lr;
            if (n < N) {
                union { uint4 u; bf16 h[8]; } tmp;
                tmp.u = *reinterpret_cast<const uint4*>(B + (size_t)n * K + k0 + lk);
                #pragma unroll
                for (int i = 0; i < 8; ++i) bv[i] = b2f(tmp.h[i]);
            } else {
                #pragma unroll
                for (int i = 0; i < 8; ++i) bv[i] = 0.f;
            }
        }
        __syncthreads();
        #pragma unroll
        for (int i = 0; i < 8; ++i) As[lk + i][lr] = av[i];
        #pragma unroll
        for (int i = 0; i < 8; ++i) Bs[lk + i][lr] = bv[i];
        __syncthreads();
        #pragma unroll
        for (int kk = 0; kk < 32; ++kk) {
            float4 a4 = *reinterpret_cast<const float4*>(&As[kk][ty]);
            float4 b4 = *reinterpret_cast<const float4*>(&Bs[kk][tx]);
            float aa[4] = {a4.x, a4.y, a4.z, a4.w};
            float bb[4] = {b4.x, b4.y, b4.z, b4.w};
            #pragma unroll
            for (int i = 0; i < 4; ++i)
                #pragma unroll
                for (int j = 0; j < 4; ++j)
                    acc[i][j] = fmaf(aa[i], bb[j], acc[i][j]);
        }
        __syncthreads();
    }
    #pragma unroll
    for (int i = 0; i < 4; ++i) {
        const size_t m = m0 + ty + i;
        #pragma unroll
        for (int j = 0; j < 4; ++j) {
            const int n = n0 + tx + j;
            if (n < N) {
                float v = acc[i][j];
                if constexpr (EPI == 1) {
                    v += aux[n];
                    v = (v > 20.f) ? v : log1pf(expf(v));   // softplus
                } else if constexpr (EPI == 2) {
                    v += aux[m * (size_t)ldc + n];          // residual x
                }
                C[m * (size_t)ldc + n] = (OT)v;
            }
        }
    }
}

// ---------------- selective scan ----------------
// 16 lanes per channel (lane = state). Block: 256 thr = 16 channels. Grid: (DINNER/16, BATCH)
// y may alias dt (in-place): per iteration, all reads of element (l,e) precede the lane-0
// write in wave program order.
__global__ __launch_bounds__(256) void scan_kernel(const bf16* __restrict__ dt,
                                                   const bf16* __restrict__ xc,
                                                   const bf16* __restrict__ z,
                                                   const float* __restrict__ dbl,
                                                   const float* __restrict__ A_log,
                                                   const float* __restrict__ D_skip,
                                                   bf16* __restrict__ y) {
    const int lane = threadIdx.x & 15;     // state index
    const int grp = threadIdx.x >> 4;      // channel within block
    const int e = blockIdx.x * 16 + grp;
    const int b = blockIdx.y;
    const float a = -__expf(A_log[e * DSTATE + lane]);
    const float dsk = D_skip[e];
    const size_t rbase = (size_t)b * SEQ_N;
    const bf16* dtp = dt + rbase * DINNER + e;
    const bf16* xcp = xc + rbase * DINNER + e;
    const bf16* zp = z + rbase * DINNER + e;
    const float* blp = dbl + rbase * 96 + DTRANK + lane;
    bf16* yp = y + rbase * DINNER + e;
    float h = 0.f;
    for (int l = 0; l < SEQ_N; ++l) {
        const float dtv = b2f(dtp[(size_t)l * DINNER]);
        const float xv = b2f(xcp[(size_t)l * DINNER]);
        const float Bv = blp[(size_t)l * 96];
        const float Cv = blp[(size_t)l * 96 + DSTATE];
        const float dA = __expf(dtv * a);
        h = fmaf(h, dA, dtv * xv * Bv);
        float p = h * Cv;
        p += __shfl_xor(p, 1, 16);
        p += __shfl_xor(p, 2, 16);
        p += __shfl_xor(p, 4, 16);
        p += __shfl_xor(p, 8, 16);
        if (lane == 0) {
            const float zv = b2f(zp[(size_t)l * DINNER]);
            const float yv = (p + dsk * xv) * (zv / (1.f + __expf(-zv)));
            yp[(size_t)l * DINNER] = f2b(yv);
        }
    }
}

extern "C" void kernel_launch(void* const* d_in, const int* in_sizes, int n_in,
                              void* d_out, int out_size, void* d_ws, size_t ws_size,
                              hipStream_t stream) {
    const float* x         = (const float*)d_in[0];  // [4,4096,1024]
    const float* in_proj_w = (const float*)d_in[1];  // [4096,1024]
    const float* conv_w    = (const float*)d_in[2];  // [2048,4]
    const float* conv_b    = (const float*)d_in[3];  // [2048]
    const float* x_proj_w  = (const float*)d_in[4];  // [96,2048]
    const float* dt_proj_w = (const float*)d_in[5];  // [2048,64]
    const float* dt_proj_b = (const float*)d_in[6];  // [2048]
    const float* A_log     = (const float*)d_in[7];  // [2048,16]
    const float* D_skip    = (const float*)d_in[8];  // [2048]
    const float* out_proj_w= (const float*)d_in[9];  // [1024,2048]
    float* out = (float*)d_out;

    // workspace layout (bytes) — total 153,812,992 (~147 MB)
    char* ws = (char*)d_ws;
    bf16*  xcraw = (bf16*)(ws + 0);            // 67,108,864  [dead after conv -> reused as dtb/y]
    bf16*  xc    = (bf16*)(ws + 67108864);     // 67,108,864
    float* dbl   = (float*)(ws + 134217728);   //  6,291,456
    bf16*  w_in  = (bf16*)(ws + 140509184);    //  8,388,608
    bf16*  w_xp  = (bf16*)(ws + 148897792);    //    393,216
    bf16*  w_dt  = (bf16*)(ws + 149291008);    //    262,144
    bf16*  w_out = (bf16*)(ws + 149553152);    //  4,194,304
    float* rscale= (float*)(ws + 153747456);   //     65,536
    bf16*  dtb   = xcraw;                      // alias (xcraw dead by then)
    bf16*  yb    = dtb;                        // scan in-place
    // z lives in d_out (64 MB bf16 == 64 MB f32 out); dead before out-proj overwrites it.
    bf16*  zbuf  = (bf16*)d_out;

    // convert weights to bf16
    f32_to_bf16_kernel<<<(4194304 + 255) / 256, 256, 0, stream>>>(in_proj_w, w_in, 4194304);
    f32_to_bf16_kernel<<<(196608 + 255) / 256, 256, 0, stream>>>(x_proj_w, w_xp, 196608);
    f32_to_bf16_kernel<<<(131072 + 255) / 256, 256, 0, stream>>>(dt_proj_w, w_dt, 131072);
    f32_to_bf16_kernel<<<(2097152 + 255) / 256, 256, 0, stream>>>(out_proj_w, w_out, 2097152);

    // 1. rmsnorm row scales
    rms_scale_kernel<<<NROWS, 256, 0, stream>>>(x, rscale);
    // 2a. xcraw = (x*rscale) @ in_proj[0:2048]^T   [16384, 2048]
    gemm_bt<0, float, bf16><<<dim3(NROWS / 64, DINNER / 64), 256, 0, stream>>>(
        x, DMODEL, rscale, w_in, xcraw, DINNER, nullptr, DINNER, DMODEL);
    // 2b. z = (x*rscale) @ in_proj[2048:4096]^T    [16384, 2048]
    gemm_bt<0, float, bf16><<<dim3(NROWS / 64, DINNER / 64), 256, 0, stream>>>(
        x, DMODEL, rscale, w_in + (size_t)DINNER * DMODEL, zbuf, DINNER, nullptr, DINNER, DMODEL);
    // 3. conv + silu -> xc [16384, 2048]
    conv_silu_kernel<<<(NROWS * DINNER) / 256, 256, 0, stream>>>(xcraw, conv_w, conv_b, xc);
    // 4. dbl = xc @ x_proj^T  [16384, 96]
    gemm_bt<0, bf16, float><<<dim3(NROWS / 64, 2), 256, 0, stream>>>(
        xc, DINNER, nullptr, w_xp, dbl, 96, nullptr, 96, DINNER);
    // 5. dt = softplus(dbl[:, :64] @ dt_proj^T + b)  [16384, 2048]  (writes over xcraw)
    gemm_bt<1, float, bf16><<<dim3(NROWS / 64, DINNER / 64), 256, 0, stream>>>(
        dbl, 96, nullptr, w_dt, dtb, DINNER, dt_proj_b, DINNER, DTRANK);
    // 6. selective scan + skip + gate -> y (in-place over dtb)
    scan_kernel<<<dim3(DINNER / 16, BATCH_N), 256, 0, stream>>>(
        dtb, xc, zbuf, dbl, A_log, D_skip, yb);
    // 7. out = x + y @ out_proj^T  [16384, 1024] (overwrites z region last)
    gemm_bt<2, bf16, float><<<dim3(NROWS / 64, DMODEL / 64), 256, 0, stream>>>(
        yb, DINNER, nullptr, w_out, out, DMODEL, x, DMODEL, DINNER);
    (void)in_sizes; (void)n_in; (void)out_size; (void)ws_size;
}

// Round 3
// 3552.440 us; speedup vs baseline: 1.9974x; 1.9974x over previous
//
#include <hip/hip_runtime.h>
#include <hip/hip_bf16.h>
#include <math.h>

typedef __hip_bfloat16 bf16;

#define BATCH_N 4
#define SEQ_N 4096
#define DMODEL 1024
#define DINNER 2048
#define DTRANK 64
#define DSTATE 16
#define NROWS (BATCH_N * SEQ_N)   // 16384
#define NCHUNK 32
#define LCHUNK (SEQ_N / NCHUNK)   // 128

__device__ __forceinline__ float b2f(bf16 v) { return __bfloat162float(v); }
__device__ __forceinline__ bf16 f2b(float v) { return __float2bfloat16(v); }

// ---------------- f32 -> bf16 convert (weights) ----------------
__global__ void f32_to_bf16_kernel(const float* __restrict__ in, bf16* __restrict__ out, int n) {
    int i = blockIdx.x * 256 + threadIdx.x;
    if (i < n) out[i] = f2b(in[i]);
}

// ---------------- RMSNorm scale per row ----------------
__global__ __launch_bounds__(256) void rms_scale_kernel(const float* __restrict__ x,
                                                        float* __restrict__ scale) {
    const int r = blockIdx.x;
    const int t = threadIdx.x;
    const float4 v = reinterpret_cast<const float4*>(x + (size_t)r * DMODEL)[t];
    float ss = v.x * v.x + v.y * v.y + v.z * v.z + v.w * v.w;
    #pragma unroll
    for (int o = 32; o > 0; o >>= 1) ss += __shfl_down(ss, o);
    __shared__ float red[4];
    if ((t & 63) == 0) red[t >> 6] = ss;
    __syncthreads();
    if (t == 0) {
        const float tot = red[0] + red[1] + red[2] + red[3];
        scale[r] = rsqrtf(tot * (1.0f / DMODEL) + 1e-6f);
    }
}

// ---------------- causal depthwise conv (width 4) + silu ----------------
__global__ __launch_bounds__(256) void conv_silu_kernel(const bf16* __restrict__ xcraw,
                                                        const float* __restrict__ cw,
                                                        const float* __restrict__ cb,
                                                        bf16* __restrict__ xc) {
    const int idx = blockIdx.x * 256 + threadIdx.x;       // (row, e)
    const int e = idx & (DINNER - 1);
    const int r = idx >> 11;
    const int l = r & (SEQ_N - 1);
    const float4 w = *reinterpret_cast<const float4*>(cw + e * 4);
    float xs[4];
    #pragma unroll
    for (int k = 0; k < 4; ++k) {
        const int lp = l - 3 + k;
        xs[k] = (lp >= 0) ? b2f(xcraw[(size_t)(r - 3 + k) * DINNER + e]) : 0.f;
    }
    const float acc = cb[e] + w.x * xs[0] + w.y * xs[1] + w.z * xs[2] + w.w * xs[3];
    xc[idx] = f2b(acc / (1.f + __expf(-acc)));
}

// ---------------- generic GEMM: C[M,N] = (ascale[m] *) A[M,K] @ B[N,K]^T (+ epilogue) ----------
template <int EPI, typename AT, typename OT>
__global__ __launch_bounds__(256) void gemm_bt(const AT* __restrict__ A, int lda,
                                               const float* __restrict__ ascale,
                                               const bf16* __restrict__ B,
                                               OT* __restrict__ C, int ldc,
                                               const float* __restrict__ aux,
                                               int N, int K) {
    __shared__ float As[32][64];
    __shared__ float Bs[32][64];
    const int m0 = blockIdx.x * 64;
    const int n0 = blockIdx.y * 64;
    const int t = threadIdx.x;
    const int lr = t >> 2;          // 0..63
    const int lk = (t & 3) * 8;     // 0,8,16,24
    const int tx = (t & 15) * 4;
    const int ty = (t >> 4) * 4;
    const float s = ascale ? ascale[m0 + lr] : 1.0f;
    float acc[4][4] = {{0.f}};
    for (int k0 = 0; k0 < K; k0 += 32) {
        float av[8], bv[8];
        if constexpr (sizeof(AT) == 2) {
            union { uint4 u; bf16 h[8]; } tmp;
            tmp.u = *reinterpret_cast<const uint4*>(A + (size_t)(m0 + lr) * lda + k0 + lk);
            #pragma unroll
            for (int i = 0; i < 8; ++i) av[i] = b2f(tmp.h[i]);
        } else {
            const float4* p = reinterpret_cast<const float4*>(A + (size_t)(m0 + lr) * lda + k0 + lk);
            float4 a0 = p[0], a1 = p[1];
            av[0] = a0.x; av[1] = a0.y; av[2] = a0.z; av[3] = a0.w;
            av[4] = a1.x; av[5] = a1.y; av[6] = a1.z; av[7] = a1.w;
        }
        if (ascale) {
            #pragma unroll
            for (int i = 0; i < 8; ++i) av[i] *= s;
        }
        {
            const int n = n0 + lr;
            if (n < N) {
                union { uint4 u; bf16 h[8]; } tmp;
                tmp.u = *reinterpret_cast<const uint4*>(B + (size_t)n * K + k0 + lk);
                #pragma unroll
                for (int i = 0; i < 8; ++i) bv[i] = b2f(tmp.h[i]);
            } else {
                #pragma unroll
                for (int i = 0; i < 8; ++i) bv[i] = 0.f;
            }
        }
        __syncthreads();
        #pragma unroll
        for (int i = 0; i < 8; ++i) As[lk + i][lr] = av[i];
        #pragma unroll
        for (int i = 0; i < 8; ++i) Bs[lk + i][lr] = bv[i];
        __syncthreads();
        #pragma unroll
        for (int kk = 0; kk < 32; ++kk) {
            float4 a4 = *reinterpret_cast<const float4*>(&As[kk][ty]);
            float4 b4 = *reinterpret_cast<const float4*>(&Bs[kk][tx]);
            float aa[4] = {a4.x, a4.y, a4.z, a4.w};
            float bb[4] = {b4.x, b4.y, b4.z, b4.w};
            #pragma unroll
            for (int i = 0; i < 4; ++i)
                #pragma unroll
                for (int j = 0; j < 4; ++j)
                    acc[i][j] = fmaf(aa[i], bb[j], acc[i][j]);
        }
        __syncthreads();
    }
    #pragma unroll
    for (int i = 0; i < 4; ++i) {
        const size_t m = m0 + ty + i;
        #pragma unroll
        for (int j = 0; j < 4; ++j) {
            const int n = n0 + tx + j;
            if (n < N) {
                float v = acc[i][j];
                if constexpr (EPI == 1) {
                    v += aux[n];
                    v = (v > 20.f) ? v : log1pf(expf(v));   // softplus
                } else if constexpr (EPI == 2) {
                    v += aux[m * (size_t)ldc + n];          // residual x
                }
                C[m * (size_t)ldc + n] = (OT)v;
            }
        }
    }
}

// ============== chunked selective scan (3 passes) ==============
// thread = one channel (16 states in registers). lane-coalesced dt/xc/z loads.

// Pass A: local scan of each chunk from h=0 -> h_end[b][c][e][16], sumdt[b][c][e]
__global__ __launch_bounds__(256) void scan_passA(const bf16* __restrict__ dt,
                                                  const bf16* __restrict__ xc,
                                                  const float* __restrict__ dbl,
                                                  const float* __restrict__ A_log,
                                                  float* __restrict__ hend,
                                                  float* __restrict__ sumdt) {
    const int e = blockIdx.x * 256 + threadIdx.x;
    const int c = blockIdx.y;
    const int b = blockIdx.z;
    float a[16], h[16];
    #pragma unroll
    for (int s = 0; s < 16; ++s) {
        a[s] = -__expf(A_log[e * 16 + s]);
        h[s] = 0.f;
    }
    float sd = 0.f;
    const size_t rbase = (size_t)b * SEQ_N + (size_t)c * LCHUNK;
    for (int i = 0; i < LCHUNK; ++i) {
        const size_t row = rbase + i;
        const float dtv = b2f(dt[row * DINNER + e]);
        const float xv = b2f(xc[row * DINNER + e]);
        const float cdx = dtv * xv;
        const float4* bp = reinterpret_cast<const float4*>(dbl + row * 96 + DTRANK);
        float Bv[16];
        *reinterpret_cast<float4*>(&Bv[0])  = bp[0];
        *reinterpret_cast<float4*>(&Bv[4])  = bp[1];
        *reinterpret_cast<float4*>(&Bv[8])  = bp[2];
        *reinterpret_cast<float4*>(&Bv[12]) = bp[3];
        sd += dtv;
        #pragma unroll
        for (int s = 0; s < 16; ++s) {
            const float dA = __expf(dtv * a[s]);
            h[s] = fmaf(h[s], dA, cdx * Bv[s]);
        }
    }
    const size_t o = ((size_t)b * NCHUNK + c) * DINNER + e;
    #pragma unroll
    for (int s = 0; s < 16; s += 4) {
        float4 v = {h[s], h[s + 1], h[s + 2], h[s + 3]};
        *reinterpret_cast<float4*>(hend + o * 16 + s) = v;
    }
    sumdt[o] = sd;
}

// Pass B: sequential combine over chunks. In-place: hstate holds hend on entry,
// Hinit (true initial state of each chunk) on exit. Thread per (b,e,s).
__global__ __launch_bounds__(256) void scan_passB(float* hstate,
                                                  const float* __restrict__ sumdt,
                                                  const float* __restrict__ A_log) {
    const int g = blockIdx.x * 256 + threadIdx.x;
    const int s = g & 15;
    const int e = (g >> 4) & (DINNER - 1);
    const int b = g >> 15;
    const float a = -__expf(A_log[e * 16 + s]);
    float H = 0.f;
    for (int c = 0; c < NCHUNK; ++c) {
        const size_t o = ((size_t)b * NCHUNK + c) * DINNER + e;
        const float he = hstate[o * 16 + s];
        const float sd = sumdt[o];
        hstate[o * 16 + s] = H;               // this chunk's initial state
        H = fmaf(H, __expf(a * sd), he);
    }
}

// Pass C: rescan each chunk from its true initial state; fuse y-dot, D-skip, silu(z) gate.
// y may alias dt (per-element read precedes write in same thread) -> no __restrict__ on those.
__global__ __launch_bounds__(256) void scan_passC(const bf16* dt,
                                                  const bf16* __restrict__ xc,
                                                  const bf16* __restrict__ z,
                                                  const float* __restrict__ dbl,
                                                  const float* __restrict__ A_log,
                                                  const float* __restrict__ D_skip,
                                                  const float* __restrict__ hinit,
                                                  bf16* y) {
    const int e = blockIdx.x * 256 + threadIdx.x;
    const int c = blockIdx.y;
    const int b = blockIdx.z;
    float a[16], h[16];
    #pragma unroll
    for (int s = 0; s < 16; ++s) a[s] = -__expf(A_log[e * 16 + s]);
    const float dsk = D_skip[e];
    const size_t o = ((size_t)b * NCHUNK + c) * DINNER + e;
    #pragma unroll
    for (int s = 0; s < 16; s += 4) {
        float4 v = *reinterpret_cast<const float4*>(hinit + o * 16 + s);
        h[s] = v.x; h[s + 1] = v.y; h[s + 2] = v.z; h[s + 3] = v.w;
    }
    const size_t rbase = (size_t)b * SEQ_N + (size_t)c * LCHUNK;
    for (int i = 0; i < LCHUNK; ++i) {
        const size_t row = rbase + i;
        const float dtv = b2f(dt[row * DINNER + e]);
        const float xv = b2f(xc[row * DINNER + e]);
        const float zv = b2f(z[row * DINNER + e]);
        const float cdx = dtv * xv;
        const float4* bp = reinterpret_cast<const float4*>(dbl + row * 96 + DTRANK);
        float Bv[16], Cv[16];
        *reinterpret_cast<float4*>(&Bv[0])  = bp[0];
        *reinterpret_cast<float4*>(&Bv[4])  = bp[1];
        *reinterpret_cast<float4*>(&Bv[8])  = bp[2];
        *reinterpret_cast<float4*>(&Bv[12]) = bp[3];
        *reinterpret_cast<float4*>(&Cv[0])  = bp[4];
        *reinterpret_cast<float4*>(&Cv[4])  = bp[5];
        *reinterpret_cast<float4*>(&Cv[8])  = bp[6];
        *reinterpret_cast<float4*>(&Cv[12]) = bp[7];
        float yv = 0.f;
        #pragma unroll
        for (int s = 0; s < 16; ++s) {
            const float dA = __expf(dtv * a[s]);
            h[s] = fmaf(h[s], dA, cdx * Bv[s]);
            yv = fmaf(h[s], Cv[s], yv);
        }
        const float g = (yv + dsk * xv) * (zv / (1.f + __expf(-zv)));
        y[row * DINNER + e] = f2b(g);
    }
}

extern "C" void kernel_launch(void* const* d_in, const int* in_sizes, int n_in,
                              void* d_out, int out_size, void* d_ws, size_t ws_size,
                              hipStream_t stream) {
    const float* x         = (const float*)d_in[0];  // [4,4096,1024]
    const float* in_proj_w = (const float*)d_in[1];  // [4096,1024]
    const float* conv_w    = (const float*)d_in[2];  // [2048,4]
    const float* conv_b    = (const float*)d_in[3];  // [2048]
    const float* x_proj_w  = (const float*)d_in[4];  // [96,2048]
    const float* dt_proj_w = (const float*)d_in[5];  // [2048,64]
    const float* dt_proj_b = (const float*)d_in[6];  // [2048]
    const float* A_log     = (const float*)d_in[7];  // [2048,16]
    const float* D_skip    = (const float*)d_in[8];  // [2048]
    const float* out_proj_w= (const float*)d_in[9];  // [1024,2048]
    float* out = (float*)d_out;

    // workspace layout (bytes) — total 171,638,784 (~164 MB)
    char* ws = (char*)d_ws;
    bf16*  xcraw = (bf16*)(ws + 0);            // 67,108,864  [dead after conv -> reused as dtb/y]
    bf16*  xc    = (bf16*)(ws + 67108864);     // 67,108,864
    float* dbl   = (float*)(ws + 134217728);   //  6,291,456
    bf16*  w_in  = (bf16*)(ws + 140509184);    //  8,388,608
    bf16*  w_xp  = (bf16*)(ws + 148897792);    //    393,216
    bf16*  w_dt  = (bf16*)(ws + 149291008);    //    262,144
    bf16*  w_out = (bf16*)(ws + 149553152);    //  4,194,304
    float* rscale= (float*)(ws + 153747456);   //     65,536
    float* hend  = (float*)(ws + 153812992);   // 16,777,216  (hend -> Hinit in-place)
    float* sumdt = (float*)(ws + 170590208);   //  1,048,576
    bf16*  dtb   = xcraw;                      // alias (xcraw dead by then)
    bf16*  yb    = dtb;                        // scan in-place
    bf16*  zbuf  = (bf16*)d_out;               // z in d_out; dead before out-proj overwrites

    // convert weights to bf16
    f32_to_bf16_kernel<<<(4194304 + 255) / 256, 256, 0, stream>>>(in_proj_w, w_in, 4194304);
    f32_to_bf16_kernel<<<(196608 + 255) / 256, 256, 0, stream>>>(x_proj_w, w_xp, 196608);
    f32_to_bf16_kernel<<<(131072 + 255) / 256, 256, 0, stream>>>(dt_proj_w, w_dt, 131072);
    f32_to_bf16_kernel<<<(2097152 + 255) / 256, 256, 0, stream>>>(out_proj_w, w_out, 2097152);

    // 1. rmsnorm row scales
    rms_scale_kernel<<<NROWS, 256, 0, stream>>>(x, rscale);
    // 2a. xcraw = (x*rscale) @ in_proj[0:2048]^T   [16384, 2048]
    gemm_bt<0, float, bf16><<<dim3(NROWS / 64, DINNER / 64), 256, 0, stream>>>(
        x, DMODEL, rscale, w_in, xcraw, DINNER, nullptr, DINNER, DMODEL);
    // 2b. z = (x*rscale) @ in_proj[2048:4096]^T    [16384, 2048]
    gemm_bt<0, float, bf16><<<dim3(NROWS / 64, DINNER / 64), 256, 0, stream>>>(
        x, DMODEL, rscale, w_in + (size_t)DINNER * DMODEL, zbuf, DINNER, nullptr, DINNER, DMODEL);
    // 3. conv + silu -> xc [16384, 2048]
    conv_silu_kernel<<<(NROWS * DINNER) / 256, 256, 0, stream>>>(xcraw, conv_w, conv_b, xc);
    // 4. dbl = xc @ x_proj^T  [16384, 96]
    gemm_bt<0, bf16, float><<<dim3(NROWS / 64, 2), 256, 0, stream>>>(
        xc, DINNER, nullptr, w_xp, dbl, 96, nullptr, 96, DINNER);
    // 5. dt = softplus(dbl[:, :64] @ dt_proj^T + b)  [16384, 2048]  (writes over xcraw)
    gemm_bt<1, float, bf16><<<dim3(NROWS / 64, DINNER / 64), 256, 0, stream>>>(
        dbl, 96, nullptr, w_dt, dtb, DINNER, dt_proj_b, DINNER, DTRANK);
    // 6. chunked selective scan
    scan_passA<<<dim3(DINNER / 256, NCHUNK, BATCH_N), 256, 0, stream>>>(
        dtb, xc, dbl, A_log, hend, sumdt);
    scan_passB<<<(BATCH_N * DINNER * DSTATE) / 256, 256, 0, stream>>>(hend, sumdt, A_log);
    scan_passC<<<dim3(DINNER / 256, NCHUNK, BATCH_N), 256, 0, stream>>>(
        dtb, xc, zbuf, dbl, A_log, D_skip, hend, yb);
    // 7. out = x + y @ out_proj^T  [16384, 1024]
    gemm_bt<2, bf16, float><<<dim3(NROWS / 64, DMODEL / 64), 256, 0, stream>>>(
        yb, DINNER, nullptr, w_out, out, DMODEL, x, DMODEL, DINNER);
    (void)in_sizes; (void)n_in; (void)out_size; (void)ws_size;
}

// Round 4
// 1044.545 us; speedup vs baseline: 6.7929x; 3.4009x over previous
//
#include <hip/hip_runtime.h>
#include <hip/hip_bf16.h>
#include <math.h>

typedef __hip_bfloat16 bf16;
typedef __attribute__((ext_vector_type(8))) short short8;   // 8 bf16 (4 VGPRs) MFMA A/B frag
typedef __attribute__((ext_vector_type(4))) float f32x4;    // MFMA C/D frag

#define BATCH_N 4
#define SEQ_N 4096
#define DMODEL 1024
#define DINNER 2048
#define DTRANK 64
#define DSTATE 16
#define NROWS (BATCH_N * SEQ_N)   // 16384
#define NCHUNK 32
#define LCHUNK (SEQ_N / NCHUNK)   // 128

__device__ __forceinline__ float b2f(bf16 v) { return __bfloat162float(v); }
__device__ __forceinline__ bf16 f2b(float v) { return __float2bfloat16(v); }

// async global->LDS, 16B per lane. ldsbase must be wave-uniform; HW adds lane*16.
__device__ __forceinline__ void gll16(const bf16* g, bf16* l) {
    __builtin_amdgcn_global_load_lds((const __attribute__((address_space(1))) unsigned int*)g,
                                     (__attribute__((address_space(3))) unsigned int*)l,
                                     16, 0, 0);
}

// ---------------- f32 -> bf16 convert (weights) ----------------
__global__ void f32_to_bf16_kernel(const float* __restrict__ in, bf16* __restrict__ out, int n) {
    int i = blockIdx.x * 256 + threadIdx.x;
    if (i < n) out[i] = f2b(in[i]);
}

// ---------------- RMSNorm (no weight): row of 1024 f32 -> bf16 u ----------------
__global__ __launch_bounds__(256) void rmsnorm_kernel(const float* __restrict__ x, bf16* __restrict__ u) {
    const int r = blockIdx.x;
    const int t = threadIdx.x;
    const float4 v = reinterpret_cast<const float4*>(x + (size_t)r * DMODEL)[t];
    float ss = v.x * v.x + v.y * v.y + v.z * v.z + v.w * v.w;
    #pragma unroll
    for (int o = 32; o > 0; o >>= 1) ss += __shfl_down(ss, o);
    __shared__ float red[4];
    if ((t & 63) == 0) red[t >> 6] = ss;
    __syncthreads();
    const float tot = red[0] + red[1] + red[2] + red[3];
    const float rs = rsqrtf(tot * (1.0f / DMODEL) + 1e-6f);
    union { uint2 u2; bf16 h[4]; } o4;
    o4.h[0] = f2b(v.x * rs); o4.h[1] = f2b(v.y * rs);
    o4.h[2] = f2b(v.z * rs); o4.h[3] = f2b(v.w * rs);
    *reinterpret_cast<uint2*>(u + (size_t)r * DMODEL + t * 4) = o4.u2;
}

// ---------------- causal depthwise conv (width 4) + silu ----------------
__global__ __launch_bounds__(256) void conv_silu_kernel(const bf16* __restrict__ xcraw,
                                                        const float* __restrict__ cw,
                                                        const float* __restrict__ cb,
                                                        bf16* __restrict__ xc) {
    const int idx = blockIdx.x * 256 + threadIdx.x;       // (row, e)
    const int e = idx & (DINNER - 1);
    const int r = idx >> 11;
    const int l = r & (SEQ_N - 1);
    const float4 w = *reinterpret_cast<const float4*>(cw + e * 4);
    float xs[4];
    #pragma unroll
    for (int k = 0; k < 4; ++k) {
        const int lp = l - 3 + k;
        xs[k] = (lp >= 0) ? b2f(xcraw[(size_t)(r - 3 + k) * DINNER + e]) : 0.f;
    }
    const float acc = cb[e] + w.x * xs[0] + w.y * xs[1] + w.z * xs[2] + w.w * xs[3];
    xc[idx] = f2b(acc / (1.f + __expf(-acc)));
}

// ============ MFMA bf16 GEMM: C[M,N] = A[M,K] @ B[N,K]^T ============
// 128x128 tile, 4 waves each 64x64, BK=32, 16x16x32 MFMA.
// LDS XOR swizzle: 16B block q of row m stored at slot q ^ ((m>>1)&3)  -> 2-way (free) b128 reads.
// EPI 0: bf16 store to Cout (ldc=N).
// EPI 2: f32 store Cout = acc + aux[m*N+n]  (residual).
// EPI 3: split bf16 store: col<2048 -> Cout, else Cout2 (both ldc=2048).
template <int EPI>
__global__ __launch_bounds__(256) void mfma_gemm(const bf16* __restrict__ A,
                                                 const bf16* __restrict__ B,
                                                 void* __restrict__ Cout,
                                                 void* __restrict__ Cout2,
                                                 const float* __restrict__ aux,
                                                 int N, int K) {
    __shared__ __align__(16) bf16 sA[128 * 32];
    __shared__ __align__(16) bf16 sB[128 * 32];
    const int tid = threadIdx.x;
    const int w = tid >> 6;
    const int lane = tid & 63;
    const int quad = lane >> 4;
    const int l15 = lane & 15;
    const int m0 = blockIdx.x * 128;
    const int n0 = blockIdx.y * 128;
    const int wm = (w >> 1) * 64;
    const int wn = (w & 1) * 64;

    f32x4 acc[4][4];
    #pragma unroll
    for (int i = 0; i < 4; ++i)
        #pragma unroll
        for (int j = 0; j < 4; ++j)
            acc[i][j] = (f32x4){0.f, 0.f, 0.f, 0.f};

    // staging: issue j covers rows j*64 + tid/4; lane's 16B slot = tid&3; fetch global
    // k-block q = slot ^ ((row>>1)&3). (row>>1)&3 == (sm>>1)&3 for both issues (j*64 -> 0 mod 8).
    const int sm = tid >> 2;
    const int q = (tid & 3) ^ ((sm >> 1) & 3);
    const bf16* gA0 = A + (size_t)(m0 + sm) * K + q * 8;
    const bf16* gA1 = gA0 + (size_t)64 * K;
    const bf16* gB0 = B + (size_t)(n0 + sm) * K + q * 8;
    const bf16* gB1 = gB0 + (size_t)64 * K;
    bf16* lA0 = sA + w * 512;          // bytes: w*1024 (+ lane*16 by HW)
    bf16* lA1 = sA + 2048 + w * 512;   // issue 1 at +4096 B
    bf16* lB0 = sB + w * 512;
    bf16* lB1 = sB + 2048 + w * 512;

    const int sw2 = (l15 >> 1) & 3;          // read-side swizzle (row>>1)&3
    const int qx = (quad ^ sw2) * 8;         // element offset of this lane's k-block

    for (int k0 = 0; k0 < K; k0 += 32) {
        gll16(gA0 + k0, lA0);
        gll16(gA1 + k0, lA1);
        gll16(gB0 + k0, lB0);
        gll16(gB1 + k0, lB1);
        __syncthreads();
        short8 af[4], bfr[4];
        #pragma unroll
        for (int f = 0; f < 4; ++f) {
            af[f]  = *reinterpret_cast<const short8*>(sA + (wm + f * 16 + l15) * 32 + qx);
            bfr[f] = *reinterpret_cast<const short8*>(sB + (wn + f * 16 + l15) * 32 + qx);
        }
        #pragma unroll
        for (int i = 0; i < 4; ++i)
            #pragma unroll
            for (int j = 0; j < 4; ++j)
                acc[i][j] = __builtin_amdgcn_mfma_f32_16x16x32_bf16(af[i], bfr[j], acc[i][j], 0, 0, 0);
        __syncthreads();
    }

    // epilogue: C/D layout col = lane&15, row = quad*4 + reg  [verified m89/m91]
    const int rbase = m0 + wm + quad * 4;
    if constexpr (EPI == 0) {
        bf16* C = (bf16*)Cout;
        #pragma unroll
        for (int i = 0; i < 4; ++i)
            #pragma unroll
            for (int r = 0; r < 4; ++r) {
                const size_t ro = (size_t)(rbase + i * 16 + r) * N;
                #pragma unroll
                for (int j = 0; j < 4; ++j)
                    C[ro + n0 + wn + j * 16 + l15] = f2b(acc[i][j][r]);
            }
    } else if constexpr (EPI == 2) {
        float* C = (float*)Cout;
        #pragma unroll
        for (int i = 0; i < 4; ++i)
            #pragma unroll
            for (int r = 0; r < 4; ++r) {
                const size_t ro = (size_t)(rbase + i * 16 + r) * N;
                #pragma unroll
                for (int j = 0; j < 4; ++j) {
                    const int c = n0 + wn + j * 16 + l15;
                    C[ro + c] = acc[i][j][r] + aux[ro + c];
                }
            }
    } else {  // EPI == 3: split columns between two bf16 outputs of width 2048
        bf16* C = (bf16*)((n0 < 2048) ? Cout : Cout2);
        const int cb = (n0 & 2047) + wn;
        #pragma unroll
        for (int i = 0; i < 4; ++i)
            #pragma unroll
            for (int r = 0; r < 4; ++r) {
                const size_t ro = (size_t)(rbase + i * 16 + r) * 2048;
                #pragma unroll
                for (int j = 0; j < 4; ++j)
                    C[ro + cb + j * 16 + l15] = f2b(acc[i][j][r]);
            }
    }
}

// ---------------- small VALU GEMM (kept for N=96 / K=64 cases) ----------------
// EPI 0: store acc. EPI 1: softplus(acc + aux[n]).
template <int EPI, typename AT, typename OT>
__global__ __launch_bounds__(256) void gemm_bt(const AT* __restrict__ A, int lda,
                                               const bf16* __restrict__ B,
                                               OT* __restrict__ C, int ldc,
                                               const float* __restrict__ aux,
                                               int N, int K) {
    __shared__ float As[32][64];
    __shared__ float Bs[32][64];
    const int m0 = blockIdx.x * 64;
    const int n0 = blockIdx.y * 64;
    const int t = threadIdx.x;
    const int lr = t >> 2;
    const int lk = (t & 3) * 8;
    const int tx = (t & 15) * 4;
    const int ty = (t >> 4) * 4;
    float acc[4][4] = {{0.f}};
    for (int k0 = 0; k0 < K; k0 += 32) {
        float av[8], bv[8];
        if constexpr (sizeof(AT) == 2) {
            union { uint4 u; bf16 h[8]; } tmp;
            tmp.u = *reinterpret_cast<const uint4*>(A + (size_t)(m0 + lr) * lda + k0 + lk);
            #pragma unroll
            for (int i = 0; i < 8; ++i) av[i] = b2f(tmp.h[i]);
        } else {
            const float4* p = reinterpret_cast<const float4*>(A + (size_t)(m0 + lr) * lda + k0 + lk);
            float4 a0 = p[0], a1 = p[1];
            av[0] = a0.x; av[1] = a0.y; av[2] = a0.z; av[3] = a0.w;
            av[4] = a1.x; av[5] = a1.y; av[6] = a1.z; av[7] = a1.w;
        }
        {
            const int n = n0 + lr;
            if (n < N) {
                union { uint4 u; bf16 h[8]; } tmp;
                tmp.u = *reinterpret_cast<const uint4*>(B + (size_t)n * K + k0 + lk);
                #pragma unroll
                for (int i = 0; i < 8; ++i) bv[i] = b2f(tmp.h[i]);
            } else {
                #pragma unroll
                for (int i = 0; i < 8; ++i) bv[i] = 0.f;
            }
        }
        __syncthreads();
        #pragma unroll
        for (int i = 0; i < 8; ++i) As[lk + i][lr] = av[i];
        #pragma unroll
        for (int i = 0; i < 8; ++i) Bs[lk + i][lr] = bv[i];
        __syncthreads();
        #pragma unroll
        for (int kk = 0; kk < 32; ++kk) {
            float4 a4 = *reinterpret_cast<const float4*>(&As[kk][ty]);
            float4 b4 = *reinterpret_cast<const float4*>(&Bs[kk][tx]);
            float aa[4] = {a4.x, a4.y, a4.z, a4.w};
            float bb[4] = {b4.x, b4.y, b4.z, b4.w};
            #pragma unroll
            for (int i = 0; i < 4; ++i)
                #pragma unroll
                for (int j = 0; j < 4; ++j)
                    acc[i][j] = fmaf(aa[i], bb[j], acc[i][j]);
        }
        __syncthreads();
    }
    #pragma unroll
    for (int i = 0; i < 4; ++i) {
        const size_t m = m0 + ty + i;
        #pragma unroll
        for (int j = 0; j < 4; ++j) {
            const int n = n0 + tx + j;
            if (n < N) {
                float v = acc[i][j];
                if constexpr (EPI == 1) {
                    v += aux[n];
                    v = (v > 20.f) ? v : log1pf(expf(v));
                }
                C[m * (size_t)ldc + n] = (OT)v;
            }
        }
    }
}

// ============== chunked selective scan (3 passes) ==============
__global__ __launch_bounds__(256) void scan_passA(const bf16* __restrict__ dt,
                                                  const bf16* __restrict__ xc,
                                                  const float* __restrict__ dbl,
                                                  const float* __restrict__ A_log,
                                                  float* __restrict__ hend,
                                                  float* __restrict__ sumdt) {
    const int e = blockIdx.x * 256 + threadIdx.x;
    const int c = blockIdx.y;
    const int b = blockIdx.z;
    float a[16], h[16];
    #pragma unroll
    for (int s = 0; s < 16; ++s) {
        a[s] = -__expf(A_log[e * 16 + s]);
        h[s] = 0.f;
    }
    float sd = 0.f;
    const size_t rbase = (size_t)b * SEQ_N + (size_t)c * LCHUNK;
    for (int i = 0; i < LCHUNK; ++i) {
        const size_t row = rbase + i;
        const float dtv = b2f(dt[row * DINNER + e]);
        const float xv = b2f(xc[row * DINNER + e]);
        const float cdx = dtv * xv;
        const float4* bp = reinterpret_cast<const float4*>(dbl + row * 96 + DTRANK);
        float Bv[16];
        *reinterpret_cast<float4*>(&Bv[0])  = bp[0];
        *reinterpret_cast<float4*>(&Bv[4])  = bp[1];
        *reinterpret_cast<float4*>(&Bv[8])  = bp[2];
        *reinterpret_cast<float4*>(&Bv[12]) = bp[3];
        sd += dtv;
        #pragma unroll
        for (int s = 0; s < 16; ++s) {
            const float dA = __expf(dtv * a[s]);
            h[s] = fmaf(h[s], dA, cdx * Bv[s]);
        }
    }
    const size_t o = ((size_t)b * NCHUNK + c) * DINNER + e;
    #pragma unroll
    for (int s = 0; s < 16; s += 4) {
        float4 v = {h[s], h[s + 1], h[s + 2], h[s + 3]};
        *reinterpret_cast<float4*>(hend + o * 16 + s) = v;
    }
    sumdt[o] = sd;
}

__global__ __launch_bounds__(256) void scan_passB(float* hstate,
                                                  const float* __restrict__ sumdt,
                                                  const float* __restrict__ A_log) {
    const int g = blockIdx.x * 256 + threadIdx.x;
    const int s = g & 15;
    const int e = (g >> 4) & (DINNER - 1);
    const int b = g >> 15;
    const float a = -__expf(A_log[e * 16 + s]);
    float H = 0.f;
    for (int c = 0; c < NCHUNK; ++c) {
        const size_t o = ((size_t)b * NCHUNK + c) * DINNER + e;
        const float he = hstate[o * 16 + s];
        const float sd = sumdt[o];
        hstate[o * 16 + s] = H;
        H = fmaf(H, __expf(a * sd), he);
    }
}

__global__ __launch_bounds__(256) void scan_passC(const bf16* dt,
                                                  const bf16* __restrict__ xc,
                                                  const bf16* __restrict__ z,
                                                  const float* __restrict__ dbl,
                                                  const float* __restrict__ A_log,
                                                  const float* __restrict__ D_skip,
                                                  const float* __restrict__ hinit,
                                                  bf16* y) {
    const int e = blockIdx.x * 256 + threadIdx.x;
    const int c = blockIdx.y;
    const int b = blockIdx.z;
    float a[16], h[16];
    #pragma unroll
    for (int s = 0; s < 16; ++s) a[s] = -__expf(A_log[e * 16 + s]);
    const float dsk = D_skip[e];
    const size_t o = ((size_t)b * NCHUNK + c) * DINNER + e;
    #pragma unroll
    for (int s = 0; s < 16; s += 4) {
        float4 v = *reinterpret_cast<const float4*>(hinit + o * 16 + s);
        h[s] = v.x; h[s + 1] = v.y; h[s + 2] = v.z; h[s + 3] = v.w;
    }
    const size_t rbase = (size_t)b * SEQ_N + (size_t)c * LCHUNK;
    for (int i = 0; i < LCHUNK; ++i) {
        const size_t row = rbase + i;
        const float dtv = b2f(dt[row * DINNER + e]);
        const float xv = b2f(xc[row * DINNER + e]);
        const float zv = b2f(z[row * DINNER + e]);
        const float cdx = dtv * xv;
        const float4* bp = reinterpret_cast<const float4*>(dbl + row * 96 + DTRANK);
        float Bv[16], Cv[16];
        *reinterpret_cast<float4*>(&Bv[0])  = bp[0];
        *reinterpret_cast<float4*>(&Bv[4])  = bp[1];
        *reinterpret_cast<float4*>(&Bv[8])  = bp[2];
        *reinterpret_cast<float4*>(&Bv[12]) = bp[3];
        *reinterpret_cast<float4*>(&Cv[0])  = bp[4];
        *reinterpret_cast<float4*>(&Cv[4])  = bp[5];
        *reinterpret_cast<float4*>(&Cv[8])  = bp[6];
        *reinterpret_cast<float4*>(&Cv[12]) = bp[7];
        float yv = 0.f;
        #pragma unroll
        for (int s = 0; s < 16; ++s) {
            const float dA = __expf(dtv * a[s]);
            h[s] = fmaf(h[s], dA, cdx * Bv[s]);
            yv = fmaf(h[s], Cv[s], yv);
        }
        const float g = (yv + dsk * xv) * (zv / (1.f + __expf(-zv)));
        y[row * DINNER + e] = f2b(g);
    }
}

extern "C" void kernel_launch(void* const* d_in, const int* in_sizes, int n_in,
                              void* d_out, int out_size, void* d_ws, size_t ws_size,
                              hipStream_t stream) {
    const float* x         = (const float*)d_in[0];
    const float* in_proj_w = (const float*)d_in[1];
    const float* conv_w    = (const float*)d_in[2];
    const float* conv_b    = (const float*)d_in[3];
    const float* x_proj_w  = (const float*)d_in[4];
    const float* dt_proj_w = (const float*)d_in[5];
    const float* dt_proj_b = (const float*)d_in[6];
    const float* A_log     = (const float*)d_in[7];
    const float* D_skip    = (const float*)d_in[8];
    const float* out_proj_w= (const float*)d_in[9];
    float* out = (float*)d_out;

    // workspace layout (bytes) — total 171,638,784 (~164 MB), same as round 3
    char* ws = (char*)d_ws;
    bf16*  xcraw = (bf16*)(ws + 0);            // 67,108,864  [-> dtb -> y]
    bf16*  xc    = (bf16*)(ws + 67108864);     // 67,108,864  [u lives here first]
    float* dbl   = (float*)(ws + 134217728);   //  6,291,456
    bf16*  w_in  = (bf16*)(ws + 140509184);    //  8,388,608
    bf16*  w_xp  = (bf16*)(ws + 148897792);    //    393,216
    bf16*  w_dt  = (bf16*)(ws + 149291008);    //    262,144
    bf16*  w_out = (bf16*)(ws + 149553152);    //  4,194,304
    // 153747456..153812992: free (was rscale)
    float* hend  = (float*)(ws + 153812992);   // 16,777,216
    float* sumdt = (float*)(ws + 170590208);   //  1,048,576
    bf16*  u     = xc;                         // u (32 MB) dies before conv writes xc
    bf16*  dtb   = xcraw;
    bf16*  yb    = dtb;
    bf16*  zbuf  = (bf16*)d_out;               // z in d_out; overwritten by out-proj last

    f32_to_bf16_kernel<<<(4194304 + 255) / 256, 256, 0, stream>>>(in_proj_w, w_in, 4194304);
    f32_to_bf16_kernel<<<(196608 + 255) / 256, 256, 0, stream>>>(x_proj_w, w_xp, 196608);
    f32_to_bf16_kernel<<<(131072 + 255) / 256, 256, 0, stream>>>(dt_proj_w, w_dt, 131072);
    f32_to_bf16_kernel<<<(2097152 + 255) / 256, 256, 0, stream>>>(out_proj_w, w_out, 2097152);

    // 1. rmsnorm -> u bf16
    rmsnorm_kernel<<<NROWS, 256, 0, stream>>>(x, u);
    // 2. xz = u @ in_proj^T, split-stored: cols [0,2048)->xcraw, [2048,4096)->zbuf
    mfma_gemm<3><<<dim3(NROWS / 128, 4096 / 128), 256, 0, stream>>>(
        u, w_in, xcraw, zbuf, nullptr, 4096, DMODEL);
    // 3. conv + silu -> xc (overwrites u; reads only xcraw)
    conv_silu_kernel<<<(NROWS * DINNER) / 256, 256, 0, stream>>>(xcraw, conv_w, conv_b, xc);
    // 4. dbl = xc @ x_proj^T  [16384, 96]
    gemm_bt<0, bf16, float><<<dim3(NROWS / 64, 2), 256, 0, stream>>>(
        xc, DINNER, w_xp, dbl, 96, nullptr, 96, DINNER);
    // 5. dt = softplus(dbl[:, :64] @ dt_proj^T + b)  [16384, 2048]  (over xcraw)
    gemm_bt<1, float, bf16><<<dim3(NROWS / 64, DINNER / 64), 256, 0, stream>>>(
        dbl, 96, w_dt, dtb, DINNER, dt_proj_b, DINNER, DTRANK);
    // 6. chunked selective scan
    scan_passA<<<dim3(DINNER / 256, NCHUNK, BATCH_N), 256, 0, stream>>>(
        dtb, xc, dbl, A_log, hend, sumdt);
    scan_passB<<<(BATCH_N * DINNER * DSTATE) / 256, 256, 0, stream>>>(hend, sumdt, A_log);
    scan_passC<<<dim3(DINNER / 256, NCHUNK, BATCH_N), 256, 0, stream>>>(
        dtb, xc, zbuf, dbl, A_log, D_skip, hend, yb);
    // 7. out = x + y @ out_proj^T  [16384, 1024]
    mfma_gemm<2><<<dim3(NROWS / 128, DMODEL / 128), 256, 0, stream>>>(
        yb, w_out, out, nullptr, x, DMODEL, DINNER);
    (void)in_sizes; (void)n_in; (void)out_size; (void)ws_size;
}

// Round 5
// 930.274 us; speedup vs baseline: 7.6273x; 1.1228x over previous
//
#include <hip/hip_runtime.h>
#include <hip/hip_bf16.h>
#include <math.h>

typedef __hip_bfloat16 bf16;
typedef __attribute__((ext_vector_type(8))) short short8;   // 8 bf16 (4 VGPRs) MFMA A/B frag
typedef __attribute__((ext_vector_type(4))) float f32x4;    // MFMA C/D frag

#define BATCH_N 4
#define SEQ_N 4096
#define DMODEL 1024
#define DINNER 2048
#define DTRANK 64
#define DSTATE 16
#define NROWS (BATCH_N * SEQ_N)   // 16384
#define NCHUNK 32
#define LCHUNK (SEQ_N / NCHUNK)   // 128

__device__ __forceinline__ float b2f(bf16 v) { return __bfloat162float(v); }
__device__ __forceinline__ bf16 f2b(float v) { return __float2bfloat16(v); }

// async global->LDS, 16B per lane. ldsbase must be wave-uniform; HW adds lane*16.
__device__ __forceinline__ void gll16(const bf16* g, bf16* l) {
    __builtin_amdgcn_global_load_lds((const __attribute__((address_space(1))) unsigned int*)g,
                                     (__attribute__((address_space(3))) unsigned int*)l,
                                     16, 0, 0);
}

// ---------------- f32 -> bf16 convert (weights) ----------------
__global__ void f32_to_bf16_kernel(const float* __restrict__ in, bf16* __restrict__ out, int n) {
    int i = blockIdx.x * 256 + threadIdx.x;
    if (i < n) out[i] = f2b(in[i]);
}

// ---------------- RMSNorm (no weight): row of 1024 f32 -> bf16 u ----------------
__global__ __launch_bounds__(256) void rmsnorm_kernel(const float* __restrict__ x, bf16* __restrict__ u) {
    const int r = blockIdx.x;
    const int t = threadIdx.x;
    const float4 v = reinterpret_cast<const float4*>(x + (size_t)r * DMODEL)[t];
    float ss = v.x * v.x + v.y * v.y + v.z * v.z + v.w * v.w;
    #pragma unroll
    for (int o = 32; o > 0; o >>= 1) ss += __shfl_down(ss, o);
    __shared__ float red[4];
    if ((t & 63) == 0) red[t >> 6] = ss;
    __syncthreads();
    const float tot = red[0] + red[1] + red[2] + red[3];
    const float rs = rsqrtf(tot * (1.0f / DMODEL) + 1e-6f);
    union { uint2 u2; bf16 h[4]; } o4;
    o4.h[0] = f2b(v.x * rs); o4.h[1] = f2b(v.y * rs);
    o4.h[2] = f2b(v.z * rs); o4.h[3] = f2b(v.w * rs);
    *reinterpret_cast<uint2*>(u + (size_t)r * DMODEL + t * 4) = o4.u2;
}

// ---------------- causal depthwise conv (width 4) + silu ----------------
__global__ __launch_bounds__(256) void conv_silu_kernel(const bf16* __restrict__ xcraw,
                                                        const float* __restrict__ cw,
                                                        const float* __restrict__ cb,
                                                        bf16* __restrict__ xc) {
    const int idx = blockIdx.x * 256 + threadIdx.x;       // (row, e)
    const int e = idx & (DINNER - 1);
    const int r = idx >> 11;
    const int l = r & (SEQ_N - 1);
    const float4 w = *reinterpret_cast<const float4*>(cw + e * 4);
    float xs[4];
    #pragma unroll
    for (int k = 0; k < 4; ++k) {
        const int lp = l - 3 + k;
        xs[k] = (lp >= 0) ? b2f(xcraw[(size_t)(r - 3 + k) * DINNER + e]) : 0.f;
    }
    const float acc = cb[e] + w.x * xs[0] + w.y * xs[1] + w.z * xs[2] + w.w * xs[3];
    xc[idx] = f2b(acc / (1.f + __expf(-acc)));
}

// ============ MFMA bf16 GEMM: C[M,N] = A[M,K] @ B[N,K]^T ============
// 128x128 tile, 4 waves each 64x64, BK=32, 16x16x32 MFMA.
// LDS XOR swizzle: 16B block q of row m stored at slot q ^ ((m>>1)&3)  -> 2-way (free) b128 reads.
// EPI 1: bf16 store, softplus(acc + aux[n])  (ldc=N).
// EPI 2: f32 store Cout = acc + aux[m*N+n]  (residual).
// EPI 3: split bf16 store: col<2048 -> Cout, else Cout2 (both ldc=2048).
// EPI 4: x_proj split: col<64 -> bf16 Cout (ldc=64); 64<=col<96 -> f32 Cout2 (ldc=32); else drop.
template <int EPI>
__global__ __launch_bounds__(256) void mfma_gemm(const bf16* __restrict__ A,
                                                 const bf16* __restrict__ B,
                                                 void* __restrict__ Cout,
                                                 void* __restrict__ Cout2,
                                                 const float* __restrict__ aux,
                                                 int N, int K) {
    __shared__ __align__(16) bf16 sA[128 * 32];
    __shared__ __align__(16) bf16 sB[128 * 32];
    const int tid = threadIdx.x;
    const int w = tid >> 6;
    const int lane = tid & 63;
    const int quad = lane >> 4;
    const int l15 = lane & 15;
    const int m0 = blockIdx.x * 128;
    const int n0 = blockIdx.y * 128;
    const int wm = (w >> 1) * 64;
    const int wn = (w & 1) * 64;

    f32x4 acc[4][4];
    #pragma unroll
    for (int i = 0; i < 4; ++i)
        #pragma unroll
        for (int j = 0; j < 4; ++j)
            acc[i][j] = (f32x4){0.f, 0.f, 0.f, 0.f};

    const int sm = tid >> 2;
    const int q = (tid & 3) ^ ((sm >> 1) & 3);
    const bf16* gA0 = A + (size_t)(m0 + sm) * K + q * 8;
    const bf16* gA1 = gA0 + (size_t)64 * K;
    const bf16* gB0 = B + (size_t)(n0 + sm) * K + q * 8;
    const bf16* gB1 = gB0 + (size_t)64 * K;
    bf16* lA0 = sA + w * 512;
    bf16* lA1 = sA + 2048 + w * 512;
    bf16* lB0 = sB + w * 512;
    bf16* lB1 = sB + 2048 + w * 512;

    const int sw2 = (l15 >> 1) & 3;
    const int qx = (quad ^ sw2) * 8;

    for (int k0 = 0; k0 < K; k0 += 32) {
        gll16(gA0 + k0, lA0);
        gll16(gA1 + k0, lA1);
        gll16(gB0 + k0, lB0);
        gll16(gB1 + k0, lB1);
        __syncthreads();
        short8 af[4], bfr[4];
        #pragma unroll
        for (int f = 0; f < 4; ++f) {
            af[f]  = *reinterpret_cast<const short8*>(sA + (wm + f * 16 + l15) * 32 + qx);
            bfr[f] = *reinterpret_cast<const short8*>(sB + (wn + f * 16 + l15) * 32 + qx);
        }
        #pragma unroll
        for (int i = 0; i < 4; ++i)
            #pragma unroll
            for (int j = 0; j < 4; ++j)
                acc[i][j] = __builtin_amdgcn_mfma_f32_16x16x32_bf16(af[i], bfr[j], acc[i][j], 0, 0, 0);
        __syncthreads();
    }

    // epilogue: C/D layout col = lane&15, row = quad*4 + reg  [verified m89/m91]
    const int rbase = m0 + wm + quad * 4;
    if constexpr (EPI == 1) {
        bf16* C = (bf16*)Cout;
        #pragma unroll
        for (int i = 0; i < 4; ++i)
            #pragma unroll
            for (int r = 0; r < 4; ++r) {
                const size_t ro = (size_t)(rbase + i * 16 + r) * N;
                #pragma unroll
                for (int j = 0; j < 4; ++j) {
                    const int c = n0 + wn + j * 16 + l15;
                    float v = acc[i][j][r] + aux[c];
                    v = (v > 20.f) ? v : log1pf(expf(v));   // softplus
                    C[ro + c] = f2b(v);
                }
            }
    } else if constexpr (EPI == 2) {
        float* C = (float*)Cout;
        #pragma unroll
        for (int i = 0; i < 4; ++i)
            #pragma unroll
            for (int r = 0; r < 4; ++r) {
                const size_t ro = (size_t)(rbase + i * 16 + r) * N;
                #pragma unroll
                for (int j = 0; j < 4; ++j) {
                    const int c = n0 + wn + j * 16 + l15;
                    C[ro + c] = acc[i][j][r] + aux[ro + c];
                }
            }
    } else if constexpr (EPI == 3) {
        bf16* C = (bf16*)((n0 < 2048) ? Cout : Cout2);
        const int cb = (n0 & 2047) + wn;
        #pragma unroll
        for (int i = 0; i < 4; ++i)
            #pragma unroll
            for (int r = 0; r < 4; ++r) {
                const size_t ro = (size_t)(rbase + i * 16 + r) * 2048;
                #pragma unroll
                for (int j = 0; j < 4; ++j)
                    C[ro + cb + j * 16 + l15] = f2b(acc[i][j][r]);
            }
    } else {  // EPI == 4
        bf16* Cd = (bf16*)Cout;     // dt-rank part, ldc 64
        float* Cbc = (float*)Cout2; // B,C part, ldc 32
        #pragma unroll
        for (int i = 0; i < 4; ++i)
            #pragma unroll
            for (int r = 0; r < 4; ++r) {
                const size_t row = (size_t)(rbase + i * 16 + r);
                #pragma unroll
                for (int j = 0; j < 4; ++j) {
                    const int c = wn + j * 16 + l15;   // n0 == 0
                    if (c < 64) Cd[row * 64 + c] = f2b(acc[i][j][r]);
                    else if (c < 96) Cbc[row * 32 + (c - 64)] = acc[i][j][r];
                }
            }
    }
}

// ============== chunked selective scan (3 passes) ==============
// bcbuf: [row][32] f32 — B at +0, C at +16.
__global__ __launch_bounds__(256) void scan_passA(const bf16* __restrict__ dt,
                                                  const bf16* __restrict__ xc,
                                                  const float* __restrict__ bcbuf,
                                                  const float* __restrict__ A_log,
                                                  float* __restrict__ hend,
                                                  float* __restrict__ sumdt) {
    const int e = blockIdx.x * 256 + threadIdx.x;
    const int c = blockIdx.y;
    const int b = blockIdx.z;
    float a[16], h[16];
    #pragma unroll
    for (int s = 0; s < 16; ++s) {
        a[s] = -__expf(A_log[e * 16 + s]);
        h[s] = 0.f;
    }
    float sd = 0.f;
    const size_t rbase = (size_t)b * SEQ_N + (size_t)c * LCHUNK;
    for (int i = 0; i < LCHUNK; ++i) {
        const size_t row = rbase + i;
        const float dtv = b2f(dt[row * DINNER + e]);
        const float xv = b2f(xc[row * DINNER + e]);
        const float cdx = dtv * xv;
        const float4* bp = reinterpret_cast<const float4*>(bcbuf + row * 32);
        float Bv[16];
        *reinterpret_cast<float4*>(&Bv[0])  = bp[0];
        *reinterpret_cast<float4*>(&Bv[4])  = bp[1];
        *reinterpret_cast<float4*>(&Bv[8])  = bp[2];
        *reinterpret_cast<float4*>(&Bv[12]) = bp[3];
        sd += dtv;
        #pragma unroll
        for (int s = 0; s < 16; ++s) {
            const float dA = __expf(dtv * a[s]);
            h[s] = fmaf(h[s], dA, cdx * Bv[s]);
        }
    }
    const size_t o = ((size_t)b * NCHUNK + c) * DINNER + e;
    #pragma unroll
    for (int s = 0; s < 16; s += 4) {
        float4 v = {h[s], h[s + 1], h[s + 2], h[s + 3]};
        *reinterpret_cast<float4*>(hend + o * 16 + s) = v;
    }
    sumdt[o] = sd;
}

__global__ __launch_bounds__(256) void scan_passB(float* hstate,
                                                  const float* __restrict__ sumdt,
                                                  const float* __restrict__ A_log) {
    const int g = blockIdx.x * 256 + threadIdx.x;
    const int s = g & 15;
    const int e = (g >> 4) & (DINNER - 1);
    const int b = g >> 15;
    const float a = -__expf(A_log[e * 16 + s]);
    float H = 0.f;
    for (int c = 0; c < NCHUNK; ++c) {
        const size_t o = ((size_t)b * NCHUNK + c) * DINNER + e;
        const float he = hstate[o * 16 + s];
        const float sd = sumdt[o];
        hstate[o * 16 + s] = H;
        H = fmaf(H, __expf(a * sd), he);
    }
}

__global__ __launch_bounds__(256) void scan_passC(const bf16* dt,
                                                  const bf16* __restrict__ xc,
                                                  const bf16* __restrict__ z,
                                                  const float* __restrict__ bcbuf,
                                                  const float* __restrict__ A_log,
                                                  const float* __restrict__ D_skip,
                                                  const float* __restrict__ hinit,
                                                  bf16* y) {
    const int e = blockIdx.x * 256 + threadIdx.x;
    const int c = blockIdx.y;
    const int b = blockIdx.z;
    float a[16], h[16];
    #pragma unroll
    for (int s = 0; s < 16; ++s) a[s] = -__expf(A_log[e * 16 + s]);
    const float dsk = D_skip[e];
    const size_t o = ((size_t)b * NCHUNK + c) * DINNER + e;
    #pragma unroll
    for (int s = 0; s < 16; s += 4) {
        float4 v = *reinterpret_cast<const float4*>(hinit + o * 16 + s);
        h[s] = v.x; h[s + 1] = v.y; h[s + 2] = v.z; h[s + 3] = v.w;
    }
    const size_t rbase = (size_t)b * SEQ_N + (size_t)c * LCHUNK;
    for (int i = 0; i < LCHUNK; ++i) {
        const size_t row = rbase + i;
        const float dtv = b2f(dt[row * DINNER + e]);
        const float xv = b2f(xc[row * DINNER + e]);
        const float zv = b2f(z[row * DINNER + e]);
        const float cdx = dtv * xv;
        const float4* bp = reinterpret_cast<const float4*>(bcbuf + row * 32);
        float Bv[16], Cv[16];
        *reinterpret_cast<float4*>(&Bv[0])  = bp[0];
        *reinterpret_cast<float4*>(&Bv[4])  = bp[1];
        *reinterpret_cast<float4*>(&Bv[8])  = bp[2];
        *reinterpret_cast<float4*>(&Bv[12]) = bp[3];
        *reinterpret_cast<float4*>(&Cv[0])  = bp[4];
        *reinterpret_cast<float4*>(&Cv[4])  = bp[5];
        *reinterpret_cast<float4*>(&Cv[8])  = bp[6];
        *reinterpret_cast<float4*>(&Cv[12]) = bp[7];
        float yv = 0.f;
        #pragma unroll
        for (int s = 0; s < 16; ++s) {
            const float dA = __expf(dtv * a[s]);
            h[s] = fmaf(h[s], dA, cdx * Bv[s]);
            yv = fmaf(h[s], Cv[s], yv);
        }
        const float g = (yv + dsk * xv) * (zv / (1.f + __expf(-zv)));
        y[row * DINNER + e] = f2b(g);
    }
}

extern "C" void kernel_launch(void* const* d_in, const int* in_sizes, int n_in,
                              void* d_out, int out_size, void* d_ws, size_t ws_size,
                              hipStream_t stream) {
    const float* x         = (const float*)d_in[0];
    const float* in_proj_w = (const float*)d_in[1];
    const float* conv_w    = (const float*)d_in[2];
    const float* conv_b    = (const float*)d_in[3];
    const float* x_proj_w  = (const float*)d_in[4];
    const float* dt_proj_w = (const float*)d_in[5];
    const float* dt_proj_b = (const float*)d_in[6];
    const float* A_log     = (const float*)d_in[7];
    const float* D_skip    = (const float*)d_in[8];
    const float* out_proj_w= (const float*)d_in[9];
    float* out = (float*)d_out;

    // workspace layout (bytes) — total ~164 MB
    char* ws = (char*)d_ws;
    bf16*  xcraw = (bf16*)(ws + 0);            // 67,108,864  [-> dtb -> y]
    bf16*  xc    = (bf16*)(ws + 67108864);     // 67,108,864  [u lives here first]
    bf16*  dtr   = (bf16*)(ws + 134217728);    //  2,097,152  [16384 x 64 bf16]
    float* bcbuf = (float*)(ws + 136314880);   //  2,097,152  [16384 x 32 f32]
    // 138412032..140509184: free
    bf16*  w_in  = (bf16*)(ws + 140509184);    //  8,388,608
    bf16*  w_xp  = (bf16*)(ws + 148897792);    //    524,288  [padded to 128 x 2048]
    bf16*  w_dt  = (bf16*)(ws + 149422080);    //    262,144
    bf16*  w_out = (bf16*)(ws + 149684224);    //  4,194,304
    float* hend  = (float*)(ws + 153878528);   // 16,777,216
    float* sumdt = (float*)(ws + 170655744);   //  1,048,576  (end 171,704,320)
    bf16*  u     = xc;                         // u (32 MB) dies before conv writes xc
    bf16*  dtb   = xcraw;
    bf16*  yb    = dtb;
    bf16*  zbuf  = (bf16*)d_out;               // z in d_out; overwritten by out-proj last

    f32_to_bf16_kernel<<<(4194304 + 255) / 256, 256, 0, stream>>>(in_proj_w, w_in, 4194304);
    f32_to_bf16_kernel<<<(196608 + 255) / 256, 256, 0, stream>>>(x_proj_w, w_xp, 196608);
    f32_to_bf16_kernel<<<(131072 + 255) / 256, 256, 0, stream>>>(dt_proj_w, w_dt, 131072);
    f32_to_bf16_kernel<<<(2097152 + 255) / 256, 256, 0, stream>>>(out_proj_w, w_out, 2097152);

    // 1. rmsnorm -> u bf16
    rmsnorm_kernel<<<NROWS, 256, 0, stream>>>(x, u);
    // 2. xz = u @ in_proj^T, split-stored: cols [0,2048)->xcraw, [2048,4096)->zbuf
    mfma_gemm<3><<<dim3(NROWS / 128, 4096 / 128), 256, 0, stream>>>(
        u, w_in, xcraw, zbuf, nullptr, 4096, DMODEL);
    // 3. conv + silu -> xc (overwrites u; reads only xcraw)
    conv_silu_kernel<<<(NROWS * DINNER) / 256, 256, 0, stream>>>(xcraw, conv_w, conv_b, xc);
    // 4. x_proj: dtr (bf16, cols 0..63) + bcbuf (f32, cols 64..95); N padded to 128
    mfma_gemm<4><<<dim3(NROWS / 128, 1), 256, 0, stream>>>(
        xc, w_xp, dtr, bcbuf, nullptr, 128, DINNER);
    // 5. dt = softplus(dtr @ dt_proj^T + b)  [16384, 2048]  (over xcraw)
    mfma_gemm<1><<<dim3(NROWS / 128, DINNER / 128), 256, 0, stream>>>(
        dtr, w_dt, dtb, nullptr, dt_proj_b, DINNER, DTRANK);
    // 6. chunked selective scan
    scan_passA<<<dim3(DINNER / 256, NCHUNK, BATCH_N), 256, 0, stream>>>(
        dtb, xc, bcbuf, A_log, hend, sumdt);
    scan_passB<<<(BATCH_N * DINNER * DSTATE) / 256, 256, 0, stream>>>(hend, sumdt, A_log);
    scan_passC<<<dim3(DINNER / 256, NCHUNK, BATCH_N), 256, 0, stream>>>(
        dtb, xc, zbuf, bcbuf, A_log, D_skip, hend, yb);
    // 7. out = x + y @ out_proj^T  [16384, 1024]
    mfma_gemm<2><<<dim3(NROWS / 128, DMODEL / 128), 256, 0, stream>>>(
        yb, w_out, out, nullptr, x, DMODEL, DINNER);
    (void)in_sizes; (void)n_in; (void)out_size; (void)ws_size;
}

// Round 6
// 770.220 us; speedup vs baseline: 9.2123x; 1.2078x over previous
//
#include <hip/hip_runtime.h>
#include <hip/hip_bf16.h>
#include <math.h>

typedef __hip_bfloat16 bf16;
typedef __attribute__((ext_vector_type(8))) short short8;   // 8 bf16 (4 VGPRs) MFMA A/B frag
typedef __attribute__((ext_vector_type(4))) float f32x4;    // MFMA C/D frag

#define BATCH_N 4
#define SEQ_N 4096
#define DMODEL 1024
#define DINNER 2048
#define DTRANK 64
#define DSTATE 16
#define NROWS (BATCH_N * SEQ_N)   // 16384

__device__ __forceinline__ float b2f(bf16 v) { return __bfloat162float(v); }
__device__ __forceinline__ bf16 f2b(float v) { return __float2bfloat16(v); }

// async global->LDS, 16B per lane. ldsbase must be wave-uniform; HW adds lane*16.
__device__ __forceinline__ void gll16(const bf16* g, bf16* l) {
    __builtin_amdgcn_global_load_lds((const __attribute__((address_space(1))) unsigned int*)g,
                                     (__attribute__((address_space(3))) unsigned int*)l,
                                     16, 0, 0);
}

// ---------------- fused f32 -> bf16 convert for all 4 weights (1 launch) ----------------
#define CVT_N1 4194304   // in_proj
#define CVT_N2 196608    // x_proj
#define CVT_N3 131072    // dt_proj
#define CVT_N4 2097152   // out_proj
__global__ void cvt_all_kernel(const float* __restrict__ i1, bf16* __restrict__ o1,
                               const float* __restrict__ i2, bf16* __restrict__ o2,
                               const float* __restrict__ i3, bf16* __restrict__ o3,
                               const float* __restrict__ i4, bf16* __restrict__ o4) {
    int i = blockIdx.x * 256 + threadIdx.x;
    if (i < CVT_N1) { o1[i] = f2b(i1[i]); }
    i -= CVT_N1;
    if (i >= 0 && i < CVT_N2) { o2[i] = f2b(i2[i]); }
    i -= CVT_N2;
    if (i >= 0 && i < CVT_N3) { o3[i] = f2b(i3[i]); }
    i -= CVT_N3;
    if (i >= 0 && i < CVT_N4) { o4[i] = f2b(i4[i]); }
}

// ---------------- RMSNorm (no weight): row of 1024 f32 -> bf16 u ----------------
__global__ __launch_bounds__(256) void rmsnorm_kernel(const float* __restrict__ x, bf16* __restrict__ u) {
    const int r = blockIdx.x;
    const int t = threadIdx.x;
    const float4 v = reinterpret_cast<const float4*>(x + (size_t)r * DMODEL)[t];
    float ss = v.x * v.x + v.y * v.y + v.z * v.z + v.w * v.w;
    #pragma unroll
    for (int o = 32; o > 0; o >>= 1) ss += __shfl_down(ss, o);
    __shared__ float red[4];
    if ((t & 63) == 0) red[t >> 6] = ss;
    __syncthreads();
    const float tot = red[0] + red[1] + red[2] + red[3];
    const float rs = rsqrtf(tot * (1.0f / DMODEL) + 1e-6f);
    union { uint2 u2; bf16 h[4]; } o4;
    o4.h[0] = f2b(v.x * rs); o4.h[1] = f2b(v.y * rs);
    o4.h[2] = f2b(v.z * rs); o4.h[3] = f2b(v.w * rs);
    *reinterpret_cast<uint2*>(u + (size_t)r * DMODEL + t * 4) = o4.u2;
}

// ---------------- causal depthwise conv (width 4) + silu ----------------
__global__ __launch_bounds__(256) void conv_silu_kernel(const bf16* __restrict__ xcraw,
                                                        const float* __restrict__ cw,
                                                        const float* __restrict__ cb,
                                                        bf16* __restrict__ xc) {
    const int idx = blockIdx.x * 256 + threadIdx.x;       // (row, e)
    const int e = idx & (DINNER - 1);
    const int r = idx >> 11;
    const int l = r & (SEQ_N - 1);
    const float4 w = *reinterpret_cast<const float4*>(cw + e * 4);
    float xs[4];
    #pragma unroll
    for (int k = 0; k < 4; ++k) {
        const int lp = l - 3 + k;
        xs[k] = (lp >= 0) ? b2f(xcraw[(size_t)(r - 3 + k) * DINNER + e]) : 0.f;
    }
    const float acc = cb[e] + w.x * xs[0] + w.y * xs[1] + w.z * xs[2] + w.w * xs[3];
    xc[idx] = f2b(acc / (1.f + __expf(-acc)));
}

// ============ MFMA bf16 GEMM: C[M,N] = A[M,K] @ B[N,K]^T ============
// 128x128 tile, 4 waves each 64x64, BK=32, 16x16x32 MFMA.
// LDS XOR swizzle: 16B block q of row m stored at slot q ^ ((m>>1)&3)  -> 2-way (free) b128 reads.
// EPI 1: bf16 store, softplus(acc + aux[n])  (ldc=N).
// EPI 2: f32 store Cout = acc + aux[m*N+n]  (residual).
// EPI 3: split bf16 store: col<2048 -> Cout, else Cout2 (both ldc=2048).
// EPI 4: x_proj split: col<64 -> bf16 Cout (ldc=64); 64<=col<96 -> f32 Cout2 (ldc=32); else drop.
template <int EPI>
__global__ __launch_bounds__(256) void mfma_gemm(const bf16* __restrict__ A,
                                                 const bf16* __restrict__ B,
                                                 void* __restrict__ Cout,
                                                 void* __restrict__ Cout2,
                                                 const float* __restrict__ aux,
                                                 int N, int K) {
    __shared__ __align__(16) bf16 sA[128 * 32];
    __shared__ __align__(16) bf16 sB[128 * 32];
    const int tid = threadIdx.x;
    const int w = tid >> 6;
    const int lane = tid & 63;
    const int quad = lane >> 4;
    const int l15 = lane & 15;
    const int m0 = blockIdx.x * 128;
    const int n0 = blockIdx.y * 128;
    const int wm = (w >> 1) * 64;
    const int wn = (w & 1) * 64;

    f32x4 acc[4][4];
    #pragma unroll
    for (int i = 0; i < 4; ++i)
        #pragma unroll
        for (int j = 0; j < 4; ++j)
            acc[i][j] = (f32x4){0.f, 0.f, 0.f, 0.f};

    const int sm = tid >> 2;
    const int q = (tid & 3) ^ ((sm >> 1) & 3);
    const bf16* gA0 = A + (size_t)(m0 + sm) * K + q * 8;
    const bf16* gA1 = gA0 + (size_t)64 * K;
    const bf16* gB0 = B + (size_t)(n0 + sm) * K + q * 8;
    const bf16* gB1 = gB0 + (size_t)64 * K;
    bf16* lA0 = sA + w * 512;
    bf16* lA1 = sA + 2048 + w * 512;
    bf16* lB0 = sB + w * 512;
    bf16* lB1 = sB + 2048 + w * 512;

    const int sw2 = (l15 >> 1) & 3;
    const int qx = (quad ^ sw2) * 8;

    for (int k0 = 0; k0 < K; k0 += 32) {
        gll16(gA0 + k0, lA0);
        gll16(gA1 + k0, lA1);
        gll16(gB0 + k0, lB0);
        gll16(gB1 + k0, lB1);
        __syncthreads();
        short8 af[4], bfr[4];
        #pragma unroll
        for (int f = 0; f < 4; ++f) {
            af[f]  = *reinterpret_cast<const short8*>(sA + (wm + f * 16 + l15) * 32 + qx);
            bfr[f] = *reinterpret_cast<const short8*>(sB + (wn + f * 16 + l15) * 32 + qx);
        }
        #pragma unroll
        for (int i = 0; i < 4; ++i)
            #pragma unroll
            for (int j = 0; j < 4; ++j)
                acc[i][j] = __builtin_amdgcn_mfma_f32_16x16x32_bf16(af[i], bfr[j], acc[i][j], 0, 0, 0);
        __syncthreads();
    }

    // epilogue: C/D layout col = lane&15, row = quad*4 + reg  [verified m89/m91]
    const int rbase = m0 + wm + quad * 4;
    if constexpr (EPI == 1) {
        bf16* C = (bf16*)Cout;
        #pragma unroll
        for (int i = 0; i < 4; ++i)
            #pragma unroll
            for (int r = 0; r < 4; ++r) {
                const size_t ro = (size_t)(rbase + i * 16 + r) * N;
                #pragma unroll
                for (int j = 0; j < 4; ++j) {
                    const int c = n0 + wn + j * 16 + l15;
                    float v = acc[i][j][r] + aux[c];
                    if (v < 15.f) v = __logf(1.f + __expf(v));   // softplus (fast, err ~1e-6)
                    C[ro + c] = f2b(v);
                }
            }
    } else if constexpr (EPI == 2) {
        float* C = (float*)Cout;
        #pragma unroll
        for (int i = 0; i < 4; ++i)
            #pragma unroll
            for (int r = 0; r < 4; ++r) {
                const size_t ro = (size_t)(rbase + i * 16 + r) * N;
                #pragma unroll
                for (int j = 0; j < 4; ++j) {
                    const int c = n0 + wn + j * 16 + l15;
                    C[ro + c] = acc[i][j][r] + aux[ro + c];
                }
            }
    } else if constexpr (EPI == 3) {
        bf16* C = (bf16*)((n0 < 2048) ? Cout : Cout2);
        const int cb = (n0 & 2047) + wn;
        #pragma unroll
        for (int i = 0; i < 4; ++i)
            #pragma unroll
            for (int r = 0; r < 4; ++r) {
                const size_t ro = (size_t)(rbase + i * 16 + r) * 2048;
                #pragma unroll
                for (int j = 0; j < 4; ++j)
                    C[ro + cb + j * 16 + l15] = f2b(acc[i][j][r]);
            }
    } else {  // EPI == 4
        bf16* Cd = (bf16*)Cout;     // dt-rank part, ldc 64
        float* Cbc = (float*)Cout2; // B,C part, ldc 32
        #pragma unroll
        for (int i = 0; i < 4; ++i)
            #pragma unroll
            for (int r = 0; r < 4; ++r) {
                const size_t row = (size_t)(rbase + i * 16 + r);
                #pragma unroll
                for (int j = 0; j < 4; ++j) {
                    const int c = wn + j * 16 + l15;   // n0 == 0
                    if (c < 64) Cd[row * 64 + c] = f2b(acc[i][j][r]);
                    else if (c < 96) Cbc[row * 32 + (c - 64)] = acc[i][j][r];
                }
            }
    }
}

// ============== chunked selective scan (3 passes), NC = chunk count ==============
// bcbuf: [row][32] f32 — B at +0, C at +16.
// exp-trick: S4D init gives a[s] = a[0]*(s+1), so exp(dtv*a[s]) = e1^(s+1), e1=exp(dtv*a[0]).
// Checked per thread against actual A_log; generic fallback keeps correctness input-independent.
__device__ __forceinline__ bool pow_ok(const float* a) {
    bool ok = true;
    #pragma unroll
    for (int s = 1; s < 16; ++s) {
        const float t = a[0] * (s + 1);
        ok = ok && (fabsf(a[s] - t) <= 1e-4f * fabsf(t) + 1e-6f);
    }
    return ok;
}

template <int NC>
__global__ __launch_bounds__(256) void scan_passA(const bf16* __restrict__ dt,
                                                  const bf16* __restrict__ xc,
                                                  const float* __restrict__ bcbuf,
                                                  const float* __restrict__ A_log,
                                                  float* __restrict__ hend,
                                                  float* __restrict__ sumdt) {
    constexpr int LC = SEQ_N / NC;
    const int e = blockIdx.x * 256 + threadIdx.x;
    const int c = blockIdx.y;
    const int b = blockIdx.z;
    float a[16], h[16];
    #pragma unroll
    for (int s = 0; s < 16; ++s) {
        a[s] = -__expf(A_log[e * 16 + s]);
        h[s] = 0.f;
    }
    const bool pw = pow_ok(a);
    float sd = 0.f;
    const size_t rbase = (size_t)b * SEQ_N + (size_t)c * LC;
    for (int i = 0; i < LC; ++i) {
        const size_t row = rbase + i;
        const float dtv = b2f(dt[row * DINNER + e]);
        const float xv = b2f(xc[row * DINNER + e]);
        const float cdx = dtv * xv;
        const float4* bp = reinterpret_cast<const float4*>(bcbuf + row * 32);
        float Bv[16];
        *reinterpret_cast<float4*>(&Bv[0])  = bp[0];
        *reinterpret_cast<float4*>(&Bv[4])  = bp[1];
        *reinterpret_cast<float4*>(&Bv[8])  = bp[2];
        *reinterpret_cast<float4*>(&Bv[12]) = bp[3];
        sd += dtv;
        if (pw) {
            const float e1 = __expf(dtv * a[0]);
            float dAp = 1.f;
            #pragma unroll
            for (int s = 0; s < 16; ++s) {
                dAp *= e1;
                h[s] = fmaf(h[s], dAp, cdx * Bv[s]);
            }
        } else {
            #pragma unroll
            for (int s = 0; s < 16; ++s) {
                const float dA = __expf(dtv * a[s]);
                h[s] = fmaf(h[s], dA, cdx * Bv[s]);
            }
        }
    }
    const size_t o = ((size_t)b * NC + c) * DINNER + e;
    #pragma unroll
    for (int s = 0; s < 16; s += 4) {
        float4 v = {h[s], h[s + 1], h[s + 2], h[s + 3]};
        *reinterpret_cast<float4*>(hend + o * 16 + s) = v;
    }
    sumdt[o] = sd;
}

template <int NC>
__global__ __launch_bounds__(256) void scan_passB(float* hstate,
                                                  const float* __restrict__ sumdt,
                                                  const float* __restrict__ A_log) {
    const int g = blockIdx.x * 256 + threadIdx.x;
    const int s = g & 15;
    const int e = (g >> 4) & (DINNER - 1);
    const int b = g >> 15;
    const float a = -__expf(A_log[e * 16 + s]);
    float H = 0.f;
    for (int c = 0; c < NC; ++c) {
        const size_t o = ((size_t)b * NC + c) * DINNER + e;
        const float he = hstate[o * 16 + s];
        const float sd = sumdt[o];
        hstate[o * 16 + s] = H;
        H = fmaf(H, __expf(a * sd), he);
    }
}

template <int NC>
__global__ __launch_bounds__(256) void scan_passC(const bf16* dt,
                                                  const bf16* __restrict__ xc,
                                                  const bf16* __restrict__ z,
                                                  const float* __restrict__ bcbuf,
                                                  const float* __restrict__ A_log,
                                                  const float* __restrict__ D_skip,
                                                  const float* __restrict__ hinit,
                                                  bf16* y) {
    constexpr int LC = SEQ_N / NC;
    const int e = blockIdx.x * 256 + threadIdx.x;
    const int c = blockIdx.y;
    const int b = blockIdx.z;
    float a[16], h[16];
    #pragma unroll
    for (int s = 0; s < 16; ++s) a[s] = -__expf(A_log[e * 16 + s]);
    const bool pw = pow_ok(a);
    const float dsk = D_skip[e];
    const size_t o = ((size_t)b * NC + c) * DINNER + e;
    #pragma unroll
    for (int s = 0; s < 16; s += 4) {
        float4 v = *reinterpret_cast<const float4*>(hinit + o * 16 + s);
        h[s] = v.x; h[s + 1] = v.y; h[s + 2] = v.z; h[s + 3] = v.w;
    }
    const size_t rbase = (size_t)b * SEQ_N + (size_t)c * LC;
    for (int i = 0; i < LC; ++i) {
        const size_t row = rbase + i;
        const float dtv = b2f(dt[row * DINNER + e]);
        const float xv = b2f(xc[row * DINNER + e]);
        const float zv = b2f(z[row * DINNER + e]);
        const float cdx = dtv * xv;
        const float4* bp = reinterpret_cast<const float4*>(bcbuf + row * 32);
        float Bv[16], Cv[16];
        *reinterpret_cast<float4*>(&Bv[0])  = bp[0];
        *reinterpret_cast<float4*>(&Bv[4])  = bp[1];
        *reinterpret_cast<float4*>(&Bv[8])  = bp[2];
        *reinterpret_cast<float4*>(&Bv[12]) = bp[3];
        *reinterpret_cast<float4*>(&Cv[0])  = bp[4];
        *reinterpret_cast<float4*>(&Cv[4])  = bp[5];
        *reinterpret_cast<float4*>(&Cv[8])  = bp[6];
        *reinterpret_cast<float4*>(&Cv[12]) = bp[7];
        float yv = 0.f;
        if (pw) {
            const float e1 = __expf(dtv * a[0]);
            float dAp = 1.f;
            #pragma unroll
            for (int s = 0; s < 16; ++s) {
                dAp *= e1;
                h[s] = fmaf(h[s], dAp, cdx * Bv[s]);
                yv = fmaf(h[s], Cv[s], yv);
            }
        } else {
            #pragma unroll
            for (int s = 0; s < 16; ++s) {
                const float dA = __expf(dtv * a[s]);
                h[s] = fmaf(h[s], dA, cdx * Bv[s]);
                yv = fmaf(h[s], Cv[s], yv);
            }
        }
        const float g = (yv + dsk * xv) * (zv / (1.f + __expf(-zv)));
        y[row * DINNER + e] = f2b(g);
    }
}

extern "C" void kernel_launch(void* const* d_in, const int* in_sizes, int n_in,
                              void* d_out, int out_size, void* d_ws, size_t ws_size,
                              hipStream_t stream) {
    const float* x         = (const float*)d_in[0];
    const float* in_proj_w = (const float*)d_in[1];
    const float* conv_w    = (const float*)d_in[2];
    const float* conv_b    = (const float*)d_in[3];
    const float* x_proj_w  = (const float*)d_in[4];
    const float* dt_proj_w = (const float*)d_in[5];
    const float* dt_proj_b = (const float*)d_in[6];
    const float* A_log     = (const float*)d_in[7];
    const float* D_skip    = (const float*)d_in[8];
    const float* out_proj_w= (const float*)d_in[9];
    float* out = (float*)d_out;

    // workspace layout (bytes)
    char* ws = (char*)d_ws;
    bf16*  xcraw = (bf16*)(ws + 0);            // 67,108,864  [-> dtb -> y]
    bf16*  xc    = (bf16*)(ws + 67108864);     // 67,108,864  [u lives here first]
    bf16*  dtr   = (bf16*)(ws + 134217728);    //  2,097,152  [16384 x 64 bf16]
    float* bcbuf = (float*)(ws + 136314880);   //  2,097,152  [16384 x 32 f32]
    bf16*  w_in  = (bf16*)(ws + 140509184);    //  8,388,608
    bf16*  w_xp  = (bf16*)(ws + 148897792);    //    524,288  [padded to 128 x 2048]
    bf16*  w_dt  = (bf16*)(ws + 149422080);    //    262,144
    bf16*  w_out = (bf16*)(ws + 149684224);    //  4,194,304
    float* hend  = (float*)(ws + 153878528);   // NC=64: 33,554,432 | NC=32: 16,777,216
    // sumdt offset depends on NC (set below)
    bf16*  u     = xc;
    bf16*  dtb   = xcraw;
    bf16*  yb    = dtb;
    bf16*  zbuf  = (bf16*)d_out;               // z in d_out; overwritten by out-proj last

    const bool big = (ws_size >= 189530112ULL);   // room for NC=64 layout?
    float* sumdt = (float*)(ws + (big ? 187432960 : 170655744));

    // weight converts (single launch)
    {
        const int total = CVT_N1 + CVT_N2 + CVT_N3 + CVT_N4;
        cvt_all_kernel<<<(total + 255) / 256, 256, 0, stream>>>(
            in_proj_w, w_in, x_proj_w, w_xp, dt_proj_w, w_dt, out_proj_w, w_out);
    }

    // 1. rmsnorm -> u bf16
    rmsnorm_kernel<<<NROWS, 256, 0, stream>>>(x, u);
    // 2. xz = u @ in_proj^T, split-stored: cols [0,2048)->xcraw, [2048,4096)->zbuf
    mfma_gemm<3><<<dim3(NROWS / 128, 4096 / 128), 256, 0, stream>>>(
        u, w_in, xcraw, zbuf, nullptr, 4096, DMODEL);
    // 3. conv + silu -> xc (overwrites u; reads only xcraw)
    conv_silu_kernel<<<(NROWS * DINNER) / 256, 256, 0, stream>>>(xcraw, conv_w, conv_b, xc);
    // 4. x_proj: dtr (bf16, cols 0..63) + bcbuf (f32, cols 64..95); N padded to 128
    mfma_gemm<4><<<dim3(NROWS / 128, 1), 256, 0, stream>>>(
        xc, w_xp, dtr, bcbuf, nullptr, 128, DINNER);
    // 5. dt = softplus(dtr @ dt_proj^T + b)  [16384, 2048]  (over xcraw)
    mfma_gemm<1><<<dim3(NROWS / 128, DINNER / 128), 256, 0, stream>>>(
        dtr, w_dt, dtb, nullptr, dt_proj_b, DINNER, DTRANK);
    // 6. chunked selective scan (NC chosen by available workspace; constant per harness)
    if (big) {
        scan_passA<64><<<dim3(DINNER / 256, 64, BATCH_N), 256, 0, stream>>>(
            dtb, xc, bcbuf, A_log, hend, sumdt);
        scan_passB<64><<<(BATCH_N * DINNER * DSTATE) / 256, 256, 0, stream>>>(hend, sumdt, A_log);
        scan_passC<64><<<dim3(DINNER / 256, 64, BATCH_N), 256, 0, stream>>>(
            dtb, xc, zbuf, bcbuf, A_log, D_skip, hend, yb);
    } else {
        scan_passA<32><<<dim3(DINNER / 256, 32, BATCH_N), 256, 0, stream>>>(
            dtb, xc, bcbuf, A_log, hend, sumdt);
        scan_passB<32><<<(BATCH_N * DINNER * DSTATE) / 256, 256, 0, stream>>>(hend, sumdt, A_log);
        scan_passC<32><<<dim3(DINNER / 256, 32, BATCH_N), 256, 0, stream>>>(
            dtb, xc, zbuf, bcbuf, A_log, D_skip, hend, yb);
    }
    // 7. out = x + y @ out_proj^T  [16384, 1024]
    mfma_gemm<2><<<dim3(NROWS / 128, DMODEL / 128), 256, 0, stream>>>(
        yb, w_out, out, nullptr, x, DMODEL, DINNER);
    (void)in_sizes; (void)n_in; (void)out_size;
}

// Round 7
// 712.640 us; speedup vs baseline: 9.9566x; 1.0808x over previous
//
#include <hip/hip_runtime.h>
#include <hip/hip_bf16.h>
#include <math.h>

typedef __hip_bfloat16 bf16;
typedef __attribute__((ext_vector_type(8))) short short8;   // 8 bf16 (4 VGPRs) MFMA A/B frag
typedef __attribute__((ext_vector_type(4))) float f32x4;    // MFMA C/D frag

#define BATCH_N 4
#define SEQ_N 4096
#define DMODEL 1024
#define DINNER 2048
#define DTRANK 64
#define DSTATE 16
#define NROWS (BATCH_N * SEQ_N)   // 16384

__device__ __forceinline__ float b2f(bf16 v) { return __bfloat162float(v); }
__device__ __forceinline__ bf16 f2b(float v) { return __float2bfloat16(v); }

// async global->LDS, 16B per lane. ldsbase must be wave-uniform; HW adds lane*16.
__device__ __forceinline__ void gll16(const bf16* g, bf16* l) {
    __builtin_amdgcn_global_load_lds((const __attribute__((address_space(1))) unsigned int*)g,
                                     (__attribute__((address_space(3))) unsigned int*)l,
                                     16, 0, 0);
}

// ---------------- fused f32 -> bf16 convert for all 4 weights (1 launch) ----------------
#define CVT_N1 4194304   // in_proj
#define CVT_N2 196608    // x_proj
#define CVT_N3 131072    // dt_proj
#define CVT_N4 2097152   // out_proj
__global__ void cvt_all_kernel(const float* __restrict__ i1, bf16* __restrict__ o1,
                               const float* __restrict__ i2, bf16* __restrict__ o2,
                               const float* __restrict__ i3, bf16* __restrict__ o3,
                               const float* __restrict__ i4, bf16* __restrict__ o4) {
    int i = blockIdx.x * 256 + threadIdx.x;
    if (i < CVT_N1) { o1[i] = f2b(i1[i]); }
    i -= CVT_N1;
    if (i >= 0 && i < CVT_N2) { o2[i] = f2b(i2[i]); }
    i -= CVT_N2;
    if (i >= 0 && i < CVT_N3) { o3[i] = f2b(i3[i]); }
    i -= CVT_N3;
    if (i >= 0 && i < CVT_N4) { o4[i] = f2b(i4[i]); }
}

// ---------------- RMSNorm (no weight): row of 1024 f32 -> bf16 u ----------------
__global__ __launch_bounds__(256) void rmsnorm_kernel(const float* __restrict__ x, bf16* __restrict__ u) {
    const int r = blockIdx.x;
    const int t = threadIdx.x;
    const float4 v = reinterpret_cast<const float4*>(x + (size_t)r * DMODEL)[t];
    float ss = v.x * v.x + v.y * v.y + v.z * v.z + v.w * v.w;
    #pragma unroll
    for (int o = 32; o > 0; o >>= 1) ss += __shfl_down(ss, o);
    __shared__ float red[4];
    if ((t & 63) == 0) red[t >> 6] = ss;
    __syncthreads();
    const float tot = red[0] + red[1] + red[2] + red[3];
    const float rs = rsqrtf(tot * (1.0f / DMODEL) + 1e-6f);
    union { uint2 u2; bf16 h[4]; } o4;
    o4.h[0] = f2b(v.x * rs); o4.h[1] = f2b(v.y * rs);
    o4.h[2] = f2b(v.z * rs); o4.h[3] = f2b(v.w * rs);
    *reinterpret_cast<uint2*>(u + (size_t)r * DMODEL + t * 4) = o4.u2;
}

// ---------------- causal depthwise conv (width 4) + silu, 4 channels/thread ----------------
__global__ __launch_bounds__(256) void conv_silu4_kernel(const bf16* __restrict__ xcraw,
                                                         const float* __restrict__ cw,
                                                         const float* __restrict__ cb,
                                                         bf16* __restrict__ xc) {
    const int t = blockIdx.x * 256 + threadIdx.x;          // over NROWS*DINNER/4
    const int e = (t << 2) & (DINNER - 1);                 // 4-aligned channel
    const int r = t >> 9;
    const int l = r & (SEQ_N - 1);
    float4 w0 = *reinterpret_cast<const float4*>(cw + (e + 0) * 4);
    float4 w1 = *reinterpret_cast<const float4*>(cw + (e + 1) * 4);
    float4 w2 = *reinterpret_cast<const float4*>(cw + (e + 2) * 4);
    float4 w3 = *reinterpret_cast<const float4*>(cw + (e + 3) * 4);
    const float4 bias = *reinterpret_cast<const float4*>(cb + e);
    float xs[4][4];   // [k][j]
    #pragma unroll
    for (int k = 0; k < 4; ++k) {
        const int lp = l - 3 + k;
        if (lp >= 0) {
            union { uint2 u; bf16 h[4]; } tmp;
            tmp.u = *reinterpret_cast<const uint2*>(xcraw + (size_t)(r - 3 + k) * DINNER + e);
            #pragma unroll
            for (int j = 0; j < 4; ++j) xs[k][j] = b2f(tmp.h[j]);
        } else {
            #pragma unroll
            for (int j = 0; j < 4; ++j) xs[k][j] = 0.f;
        }
    }
    float acc[4];
    acc[0] = bias.x + w0.x * xs[0][0] + w0.y * xs[1][0] + w0.z * xs[2][0] + w0.w * xs[3][0];
    acc[1] = bias.y + w1.x * xs[0][1] + w1.y * xs[1][1] + w1.z * xs[2][1] + w1.w * xs[3][1];
    acc[2] = bias.z + w2.x * xs[0][2] + w2.y * xs[1][2] + w2.z * xs[2][2] + w2.w * xs[3][2];
    acc[3] = bias.w + w3.x * xs[0][3] + w3.y * xs[1][3] + w3.z * xs[2][3] + w3.w * xs[3][3];
    union { uint2 u; bf16 h[4]; } o;
    #pragma unroll
    for (int j = 0; j < 4; ++j) o.h[j] = f2b(acc[j] / (1.f + __expf(-acc[j])));
    *reinterpret_cast<uint2*>(xc + (size_t)r * DINNER + e) = o.u;
}

// ============ MFMA bf16 GEMM: C[M,N] = A[M,K] @ B[N,K]^T ============
// 128x128 tile, 4 waves each 64x64, BK=64 (two 32-wide chunks per barrier period).
// LDS XOR swizzle: 16B block q of row m stored at slot q ^ ((m>>1)&3)  -> 2-way (free) b128 reads.
// EPI 1: bf16 store, softplus(acc + aux[n])  (ldc=N).
// EPI 2: f32 store Cout = acc + aux[m*N+n]  (residual).
// EPI 3: split bf16 store: col<2048 -> Cout, else Cout2 (both ldc=2048).
// EPI 5: split-K partial: f32 store to Cout + blockIdx.z*NROWS*N, A/B advanced by z*K.
template <int EPI>
__global__ __launch_bounds__(256) void mfma_gemm(const bf16* __restrict__ A, int lda,
                                                 const bf16* __restrict__ B, int ldb,
                                                 void* __restrict__ Cout,
                                                 void* __restrict__ Cout2,
                                                 const float* __restrict__ aux,
                                                 int N, int K) {
    __shared__ __align__(16) bf16 sA[2][128 * 32];
    __shared__ __align__(16) bf16 sB[2][128 * 32];
    const int tid = threadIdx.x;
    const int w = tid >> 6;
    const int lane = tid & 63;
    const int quad = lane >> 4;
    const int l15 = lane & 15;
    const int m0 = blockIdx.x * 128;
    const int n0 = blockIdx.y * 128;
    const int wm = (w >> 1) * 64;
    const int wn = (w & 1) * 64;

    if constexpr (EPI == 5) {   // split-K: this block handles K-half blockIdx.z
        const int koff = blockIdx.z * K;
        A += koff;
        B += koff;
    }

    f32x4 acc[4][4];
    #pragma unroll
    for (int i = 0; i < 4; ++i)
        #pragma unroll
        for (int j = 0; j < 4; ++j)
            acc[i][j] = (f32x4){0.f, 0.f, 0.f, 0.f};

    const int sm = tid >> 2;
    const int q = (tid & 3) ^ ((sm >> 1) & 3);
    const bf16* gA0 = A + (size_t)(m0 + sm) * lda + q * 8;
    const bf16* gA1 = gA0 + (size_t)64 * lda;
    const bf16* gB0 = B + (size_t)(n0 + sm) * ldb + q * 8;
    const bf16* gB1 = gB0 + (size_t)64 * ldb;
    bf16* lA0c0 = sA[0] + w * 512;
    bf16* lA1c0 = sA[0] + 2048 + w * 512;
    bf16* lA0c1 = sA[1] + w * 512;
    bf16* lA1c1 = sA[1] + 2048 + w * 512;
    bf16* lB0c0 = sB[0] + w * 512;
    bf16* lB1c0 = sB[0] + 2048 + w * 512;
    bf16* lB0c1 = sB[1] + w * 512;
    bf16* lB1c1 = sB[1] + 2048 + w * 512;

    const int sw2 = (l15 >> 1) & 3;
    const int qx = (quad ^ sw2) * 8;

    for (int k0 = 0; k0 < K; k0 += 64) {
        gll16(gA0 + k0, lA0c0);
        gll16(gA1 + k0, lA1c0);
        gll16(gB0 + k0, lB0c0);
        gll16(gB1 + k0, lB1c0);
        gll16(gA0 + k0 + 32, lA0c1);
        gll16(gA1 + k0 + 32, lA1c1);
        gll16(gB0 + k0 + 32, lB0c1);
        gll16(gB1 + k0 + 32, lB1c1);
        __syncthreads();
        #pragma unroll
        for (int ch = 0; ch < 2; ++ch) {
            short8 af[4], bfr[4];
            #pragma unroll
            for (int f = 0; f < 4; ++f) {
                af[f]  = *reinterpret_cast<const short8*>(sA[ch] + (wm + f * 16 + l15) * 32 + qx);
                bfr[f] = *reinterpret_cast<const short8*>(sB[ch] + (wn + f * 16 + l15) * 32 + qx);
            }
            #pragma unroll
            for (int i = 0; i < 4; ++i)
                #pragma unroll
                for (int j = 0; j < 4; ++j)
                    acc[i][j] = __builtin_amdgcn_mfma_f32_16x16x32_bf16(af[i], bfr[j], acc[i][j], 0, 0, 0);
        }
        __syncthreads();
    }

    // epilogue: C/D layout col = lane&15, row = quad*4 + reg  [verified m89/m91]
    const int rbase = m0 + wm + quad * 4;
    if constexpr (EPI == 1) {
        bf16* C = (bf16*)Cout;
        #pragma unroll
        for (int i = 0; i < 4; ++i)
            #pragma unroll
            for (int r = 0; r < 4; ++r) {
                const size_t ro = (size_t)(rbase + i * 16 + r) * N;
                #pragma unroll
                for (int j = 0; j < 4; ++j) {
                    const int c = n0 + wn + j * 16 + l15;
                    float v = acc[i][j][r] + aux[c];
                    if (v < 15.f) v = __logf(1.f + __expf(v));   // softplus (fast, err ~1e-6)
                    C[ro + c] = f2b(v);
                }
            }
    } else if constexpr (EPI == 2) {
        float* C = (float*)Cout;
        #pragma unroll
        for (int i = 0; i < 4; ++i)
            #pragma unroll
            for (int r = 0; r < 4; ++r) {
                const size_t ro = (size_t)(rbase + i * 16 + r) * N;
                #pragma unroll
                for (int j = 0; j < 4; ++j) {
                    const int c = n0 + wn + j * 16 + l15;
                    C[ro + c] = acc[i][j][r] + aux[ro + c];
                }
            }
    } else if constexpr (EPI == 3) {
        bf16* C = (bf16*)((n0 < 2048) ? Cout : Cout2);
        const int cb = (n0 & 2047) + wn;
        #pragma unroll
        for (int i = 0; i < 4; ++i)
            #pragma unroll
            for (int r = 0; r < 4; ++r) {
                const size_t ro = (size_t)(rbase + i * 16 + r) * 2048;
                #pragma unroll
                for (int j = 0; j < 4; ++j)
                    C[ro + cb + j * 16 + l15] = f2b(acc[i][j][r]);
            }
    } else {  // EPI == 5: f32 partial store (split-K)
        float* C = (float*)Cout + (size_t)blockIdx.z * NROWS * N;
        #pragma unroll
        for (int i = 0; i < 4; ++i)
            #pragma unroll
            for (int r = 0; r < 4; ++r) {
                const size_t ro = (size_t)(rbase + i * 16 + r) * N;
                #pragma unroll
                for (int j = 0; j < 4; ++j)
                    C[ro + n0 + wn + j * 16 + l15] = acc[i][j][r];
            }
    }
}

// ---------------- x_proj split-K combine: p0+p1 -> dtr (bf16) + bcbuf (f32) ----------------
__global__ __launch_bounds__(256) void combine_xproj(const float* __restrict__ p0,
                                                     const float* __restrict__ p1,
                                                     bf16* __restrict__ dtr,
                                                     float* __restrict__ bcbuf) {
    const int idx = blockIdx.x * 256 + threadIdx.x;   // over NROWS*128
    const int c = idx & 127;
    const int row = idx >> 7;
    const float v = p0[idx] + p1[idx];
    if (c < 64) dtr[(size_t)row * 64 + c] = f2b(v);
    else if (c < 96) bcbuf[(size_t)row * 32 + (c - 64)] = v;
}

// ============== chunked selective scan (3 passes), NC = chunk count ==============
// bcbuf: [row][32] f32 — B at +0, C at +16.
// exp-trick: S4D init gives a[s] = a[0]*(s+1), so exp(dtv*a[s]) = e1^(s+1), e1=exp(dtv*a[0]).
// Checked per thread against actual A_log; generic fallback keeps correctness input-independent.
__device__ __forceinline__ bool pow_ok(const float* a) {
    bool ok = true;
    #pragma unroll
    for (int s = 1; s < 16; ++s) {
        const float t = a[0] * (s + 1);
        ok = ok && (fabsf(a[s] - t) <= 1e-4f * fabsf(t) + 1e-6f);
    }
    return ok;
}

template <int NC>
__global__ __launch_bounds__(256) void scan_passA(const bf16* __restrict__ dt,
                                                  const bf16* __restrict__ xc,
                                                  const float* __restrict__ bcbuf,
                                                  const float* __restrict__ A_log,
                                                  float* __restrict__ hend,
                                                  float* __restrict__ sumdt) {
    constexpr int LC = SEQ_N / NC;
    const int e = blockIdx.x * 256 + threadIdx.x;
    const int c = blockIdx.y;
    const int b = blockIdx.z;
    float a[16], h[16];
    #pragma unroll
    for (int s = 0; s < 16; ++s) {
        a[s] = -__expf(A_log[e * 16 + s]);
        h[s] = 0.f;
    }
    const bool pw = pow_ok(a);
    float sd = 0.f;
    const size_t rbase = (size_t)b * SEQ_N + (size_t)c * LC;
    for (int i = 0; i < LC; ++i) {
        const size_t row = rbase + i;
        const float dtv = b2f(dt[row * DINNER + e]);
        const float xv = b2f(xc[row * DINNER + e]);
        const float cdx = dtv * xv;
        const float4* bp = reinterpret_cast<const float4*>(bcbuf + row * 32);
        float Bv[16];
        *reinterpret_cast<float4*>(&Bv[0])  = bp[0];
        *reinterpret_cast<float4*>(&Bv[4])  = bp[1];
        *reinterpret_cast<float4*>(&Bv[8])  = bp[2];
        *reinterpret_cast<float4*>(&Bv[12]) = bp[3];
        sd += dtv;
        if (pw) {
            const float e1 = __expf(dtv * a[0]);
            float dAp = 1.f;
            #pragma unroll
            for (int s = 0; s < 16; ++s) {
                dAp *= e1;
                h[s] = fmaf(h[s], dAp, cdx * Bv[s]);
            }
        } else {
            #pragma unroll
            for (int s = 0; s < 16; ++s) {
                const float dA = __expf(dtv * a[s]);
                h[s] = fmaf(h[s], dA, cdx * Bv[s]);
            }
        }
    }
    const size_t o = ((size_t)b * NC + c) * DINNER + e;
    #pragma unroll
    for (int s = 0; s < 16; s += 4) {
        float4 v = {h[s], h[s + 1], h[s + 2], h[s + 3]};
        *reinterpret_cast<float4*>(hend + o * 16 + s) = v;
    }
    sumdt[o] = sd;
}

template <int NC>
__global__ __launch_bounds__(256) void scan_passB(float* hstate,
                                                  const float* __restrict__ sumdt,
                                                  const float* __restrict__ A_log) {
    const int g = blockIdx.x * 256 + threadIdx.x;
    const int s = g & 15;
    const int e = (g >> 4) & (DINNER - 1);
    const int b = g >> 15;
    const float a = -__expf(A_log[e * 16 + s]);
    float H = 0.f;
    for (int c = 0; c < NC; ++c) {
        const size_t o = ((size_t)b * NC + c) * DINNER + e;
        const float he = hstate[o * 16 + s];
        const float sd = sumdt[o];
        hstate[o * 16 + s] = H;
        H = fmaf(H, __expf(a * sd), he);
    }
}

template <int NC>
__global__ __launch_bounds__(256) void scan_passC(const bf16* dt,
                                                  const bf16* __restrict__ xc,
                                                  const bf16* __restrict__ z,
                                                  const float* __restrict__ bcbuf,
                                                  const float* __restrict__ A_log,
                                                  const float* __restrict__ D_skip,
                                                  const float* __restrict__ hinit,
                                                  bf16* y) {
    constexpr int LC = SEQ_N / NC;
    const int e = blockIdx.x * 256 + threadIdx.x;
    const int c = blockIdx.y;
    const int b = blockIdx.z;
    float a[16], h[16];
    #pragma unroll
    for (int s = 0; s < 16; ++s) a[s] = -__expf(A_log[e * 16 + s]);
    const bool pw = pow_ok(a);
    const float dsk = D_skip[e];
    const size_t o = ((size_t)b * NC + c) * DINNER + e;
    #pragma unroll
    for (int s = 0; s < 16; s += 4) {
        float4 v = *reinterpret_cast<const float4*>(hinit + o * 16 + s);
        h[s] = v.x; h[s + 1] = v.y; h[s + 2] = v.z; h[s + 3] = v.w;
    }
    const size_t rbase = (size_t)b * SEQ_N + (size_t)c * LC;
    for (int i = 0; i < LC; ++i) {
        const size_t row = rbase + i;
        const float dtv = b2f(dt[row * DINNER + e]);
        const float xv = b2f(xc[row * DINNER + e]);
        const float zv = b2f(z[row * DINNER + e]);
        const float cdx = dtv * xv;
        const float4* bp = reinterpret_cast<const float4*>(bcbuf + row * 32);
        float Bv[16], Cv[16];
        *reinterpret_cast<float4*>(&Bv[0])  = bp[0];
        *reinterpret_cast<float4*>(&Bv[4])  = bp[1];
        *reinterpret_cast<float4*>(&Bv[8])  = bp[2];
        *reinterpret_cast<float4*>(&Bv[12]) = bp[3];
        *reinterpret_cast<float4*>(&Cv[0])  = bp[4];
        *reinterpret_cast<float4*>(&Cv[4])  = bp[5];
        *reinterpret_cast<float4*>(&Cv[8])  = bp[6];
        *reinterpret_cast<float4*>(&Cv[12]) = bp[7];
        float yv = 0.f;
        if (pw) {
            const float e1 = __expf(dtv * a[0]);
            float dAp = 1.f;
            #pragma unroll
            for (int s = 0; s < 16; ++s) {
                dAp *= e1;
                h[s] = fmaf(h[s], dAp, cdx * Bv[s]);
                yv = fmaf(h[s], Cv[s], yv);
            }
        } else {
            #pragma unroll
            for (int s = 0; s < 16; ++s) {
                const float dA = __expf(dtv * a[s]);
                h[s] = fmaf(h[s], dA, cdx * Bv[s]);
                yv = fmaf(h[s], Cv[s], yv);
            }
        }
        const float g = (yv + dsk * xv) * (zv / (1.f + __expf(-zv)));
        y[row * DINNER + e] = f2b(g);
    }
}

extern "C" void kernel_launch(void* const* d_in, const int* in_sizes, int n_in,
                              void* d_out, int out_size, void* d_ws, size_t ws_size,
                              hipStream_t stream) {
    const float* x         = (const float*)d_in[0];
    const float* in_proj_w = (const float*)d_in[1];
    const float* conv_w    = (const float*)d_in[2];
    const float* conv_b    = (const float*)d_in[3];
    const float* x_proj_w  = (const float*)d_in[4];
    const float* dt_proj_w = (const float*)d_in[5];
    const float* dt_proj_b = (const float*)d_in[6];
    const float* A_log     = (const float*)d_in[7];
    const float* D_skip    = (const float*)d_in[8];
    const float* out_proj_w= (const float*)d_in[9];
    float* out = (float*)d_out;

    // workspace layout (bytes)
    char* ws = (char*)d_ws;
    bf16*  xcraw = (bf16*)(ws + 0);            // 67,108,864  [-> dtb -> y]
    bf16*  xc    = (bf16*)(ws + 67108864);     // 67,108,864  [u lives here first]
    bf16*  dtr   = (bf16*)(ws + 134217728);    //  2,097,152  [16384 x 64 bf16]
    float* bcbuf = (float*)(ws + 136314880);   //  2,097,152  [16384 x 32 f32]
    bf16*  w_in  = (bf16*)(ws + 140509184);    //  8,388,608
    bf16*  w_xp  = (bf16*)(ws + 148897792);    //    524,288  [padded to 128 x 2048]
    bf16*  w_dt  = (bf16*)(ws + 149422080);    //    262,144
    bf16*  w_out = (bf16*)(ws + 149684224);    //  4,194,304
    float* hend  = (float*)(ws + 153878528);   // NC=64: 33,554,432 | NC=32: 16,777,216
    bf16*  u     = xc;
    bf16*  dtb   = xcraw;
    bf16*  yb    = dtb;
    bf16*  zbuf  = (bf16*)d_out;               // z in d_out; overwritten by out-proj last
    // x_proj split-K partials alias hend (dead until scanA): 2 x 8 MB f32
    float* xp_p0 = hend;
    float* xp_p1 = hend + (size_t)NROWS * 128;

    const bool big = (ws_size >= 189530112ULL);   // room for NC=64 layout?
    float* sumdt = (float*)(ws + (big ? 187432960 : 170655744));

    // weight converts (single launch)
    {
        const int total = CVT_N1 + CVT_N2 + CVT_N3 + CVT_N4;
        cvt_all_kernel<<<(total + 255) / 256, 256, 0, stream>>>(
            in_proj_w, w_in, x_proj_w, w_xp, dt_proj_w, w_dt, out_proj_w, w_out);
    }

    // 1. rmsnorm -> u bf16
    rmsnorm_kernel<<<NROWS, 256, 0, stream>>>(x, u);
    // 2. xz = u @ in_proj^T, split-stored: cols [0,2048)->xcraw, [2048,4096)->zbuf
    mfma_gemm<3><<<dim3(NROWS / 128, 4096 / 128), 256, 0, stream>>>(
        u, DMODEL, w_in, DMODEL, xcraw, zbuf, nullptr, 4096, DMODEL);
    // 3. conv + silu -> xc (overwrites u; reads only xcraw)
    conv_silu4_kernel<<<(NROWS * DINNER) / 1024, 256, 0, stream>>>(xcraw, conv_w, conv_b, xc);
    // 4. x_proj split-K=2: partials (f32, N=128) -> combine into dtr + bcbuf
    mfma_gemm<5><<<dim3(NROWS / 128, 1, 2), 256, 0, stream>>>(
        xc, DINNER, w_xp, DINNER, xp_p0, nullptr, nullptr, 128, DINNER / 2);
    combine_xproj<<<(NROWS * 128) / 256, 256, 0, stream>>>(xp_p0, xp_p1, dtr, bcbuf);
    // 5. dt = softplus(dtr @ dt_proj^T + b)  [16384, 2048]  (over xcraw)
    mfma_gemm<1><<<dim3(NROWS / 128, DINNER / 128), 256, 0, stream>>>(
        dtr, DTRANK, w_dt, DTRANK, dtb, nullptr, dt_proj_b, DINNER, DTRANK);
    // 6. chunked selective scan (NC chosen by available workspace; constant per harness)
    if (big) {
        scan_passA<64><<<dim3(DINNER / 256, 64, BATCH_N), 256, 0, stream>>>(
            dtb, xc, bcbuf, A_log, hend, sumdt);
        scan_passB<64><<<(BATCH_N * DINNER * DSTATE) / 256, 256, 0, stream>>>(hend, sumdt, A_log);
        scan_passC<64><<<dim3(DINNER / 256, 64, BATCH_N), 256, 0, stream>>>(
            dtb, xc, zbuf, bcbuf, A_log, D_skip, hend, yb);
    } else {
        scan_passA<32><<<dim3(DINNER / 256, 32, BATCH_N), 256, 0, stream>>>(
            dtb, xc, bcbuf, A_log, hend, sumdt);
        scan_passB<32><<<(BATCH_N * DINNER * DSTATE) / 256, 256, 0, stream>>>(hend, sumdt, A_log);
        scan_passC<32><<<dim3(DINNER / 256, 32, BATCH_N), 256, 0, stream>>>(
            dtb, xc, zbuf, bcbuf, A_log, D_skip, hend, yb);
    }
    // 7. out = x + y @ out_proj^T  [16384, 1024]
    mfma_gemm<2><<<dim3(NROWS / 128, DMODEL / 128), 256, 0, stream>>>(
        yb, DINNER, w_out, DINNER, out, nullptr, x, DMODEL, DINNER);
    (void)in_sizes; (void)n_in; (void)out_size;
}

// Round 8
// 693.251 us; speedup vs baseline: 10.2351x; 1.0280x over previous
//
#include <hip/hip_runtime.h>
#include <hip/hip_bf16.h>
#include <math.h>

typedef __hip_bfloat16 bf16;
typedef __attribute__((ext_vector_type(8))) short short8;   // 8 bf16 (4 VGPRs) MFMA A/B frag
typedef __attribute__((ext_vector_type(4))) float f32x4;    // MFMA C/D frag

#define BATCH_N 4
#define SEQ_N 4096
#define DMODEL 1024
#define DINNER 2048
#define DTRANK 64
#define DSTATE 16
#define NROWS (BATCH_N * SEQ_N)   // 16384

__device__ __forceinline__ float b2f(bf16 v) { return __bfloat162float(v); }
__device__ __forceinline__ bf16 f2b(float v) { return __float2bfloat16(v); }

// async global->LDS, 16B per lane. ldsbase must be wave-uniform; HW adds lane*16.
__device__ __forceinline__ void gll16(const bf16* g, bf16* l) {
    __builtin_amdgcn_global_load_lds((const __attribute__((address_space(1))) unsigned int*)g,
                                     (__attribute__((address_space(3))) unsigned int*)l,
                                     16, 0, 0);
}

// ---------------- prep: rmsnorm (blocks 0..NROWS) + weight cvt (rest), 1 launch ----------------
#define CVT_N1 4194304   // in_proj
#define CVT_N2 196608    // x_proj
#define CVT_N3 131072    // dt_proj
#define CVT_N4 2097152   // out_proj
#define CVT_TOTAL (CVT_N1 + CVT_N2 + CVT_N3 + CVT_N4)   // 6,619,136 (/256 = 25856 blocks)
__global__ __launch_bounds__(256) void prep_kernel(const float* __restrict__ x, bf16* __restrict__ u,
                                                   const float* __restrict__ i1, bf16* __restrict__ o1,
                                                   const float* __restrict__ i2, bf16* __restrict__ o2,
                                                   const float* __restrict__ i3, bf16* __restrict__ o3,
                                                   const float* __restrict__ i4, bf16* __restrict__ o4) {
    if (blockIdx.x < NROWS) {
        const int r = blockIdx.x;
        const int t = threadIdx.x;
        const float4 v = reinterpret_cast<const float4*>(x + (size_t)r * DMODEL)[t];
        float ss = v.x * v.x + v.y * v.y + v.z * v.z + v.w * v.w;
        #pragma unroll
        for (int o = 32; o > 0; o >>= 1) ss += __shfl_down(ss, o);
        __shared__ float red[4];
        if ((t & 63) == 0) red[t >> 6] = ss;
        __syncthreads();
        const float tot = red[0] + red[1] + red[2] + red[3];
        const float rs = rsqrtf(tot * (1.0f / DMODEL) + 1e-6f);
        union { uint2 u2; bf16 h[4]; } o4v;
        o4v.h[0] = f2b(v.x * rs); o4v.h[1] = f2b(v.y * rs);
        o4v.h[2] = f2b(v.z * rs); o4v.h[3] = f2b(v.w * rs);
        *reinterpret_cast<uint2*>(u + (size_t)r * DMODEL + t * 4) = o4v.u2;
    } else {
        int i = (blockIdx.x - NROWS) * 256 + threadIdx.x;
        if (i < CVT_N1) { o1[i] = f2b(i1[i]); }
        i -= CVT_N1;
        if (i >= 0 && i < CVT_N2) { o2[i] = f2b(i2[i]); }
        i -= CVT_N2;
        if (i >= 0 && i < CVT_N3) { o3[i] = f2b(i3[i]); }
        i -= CVT_N3;
        if (i >= 0 && i < CVT_N4) { o4[i] = f2b(i4[i]); }
    }
}

// ---------------- causal depthwise conv (width 4) + silu, 4 channels/thread ----------------
__global__ __launch_bounds__(256) void conv_silu4_kernel(const bf16* __restrict__ xcraw,
                                                         const float* __restrict__ cw,
                                                         const float* __restrict__ cb,
                                                         bf16* __restrict__ xc) {
    const int t = blockIdx.x * 256 + threadIdx.x;          // over NROWS*DINNER/4
    const int e = (t << 2) & (DINNER - 1);                 // 4-aligned channel
    const int r = t >> 9;
    const int l = r & (SEQ_N - 1);
    float4 w0 = *reinterpret_cast<const float4*>(cw + (e + 0) * 4);
    float4 w1 = *reinterpret_cast<const float4*>(cw + (e + 1) * 4);
    float4 w2 = *reinterpret_cast<const float4*>(cw + (e + 2) * 4);
    float4 w3 = *reinterpret_cast<const float4*>(cw + (e + 3) * 4);
    const float4 bias = *reinterpret_cast<const float4*>(cb + e);
    float xs[4][4];   // [k][j]
    #pragma unroll
    for (int k = 0; k < 4; ++k) {
        const int lp = l - 3 + k;
        if (lp >= 0) {
            union { uint2 u; bf16 h[4]; } tmp;
            tmp.u = *reinterpret_cast<const uint2*>(xcraw + (size_t)(r - 3 + k) * DINNER + e);
            #pragma unroll
            for (int j = 0; j < 4; ++j) xs[k][j] = b2f(tmp.h[j]);
        } else {
            #pragma unroll
            for (int j = 0; j < 4; ++j) xs[k][j] = 0.f;
        }
    }
    float acc[4];
    acc[0] = bias.x + w0.x * xs[0][0] + w0.y * xs[1][0] + w0.z * xs[2][0] + w0.w * xs[3][0];
    acc[1] = bias.y + w1.x * xs[0][1] + w1.y * xs[1][1] + w1.z * xs[2][1] + w1.w * xs[3][1];
    acc[2] = bias.z + w2.x * xs[0][2] + w2.y * xs[1][2] + w2.z * xs[2][2] + w2.w * xs[3][2];
    acc[3] = bias.w + w3.x * xs[0][3] + w3.y * xs[1][3] + w3.z * xs[2][3] + w3.w * xs[3][3];
    union { uint2 u; bf16 h[4]; } o;
    #pragma unroll
    for (int j = 0; j < 4; ++j) o.h[j] = f2b(acc[j] / (1.f + __expf(-acc[j])));
    *reinterpret_cast<uint2*>(xc + (size_t)r * DINNER + e) = o.u;
}

// ============ MFMA bf16 GEMM: C[M,N] = A[M,K] @ B[N,K]^T ============
// 128x128 tile, 4 waves each 64x64, BK=64 (two 32-wide chunks per barrier period).
// LDS XOR swizzle: 16B block q of row m stored at slot q ^ ((m>>1)&3)  -> 2-way (free) b128 reads.
// EPI 1: bf16 store, softplus(acc + aux[n])  (ldc=N).
// EPI 2: f32 store Cout = acc + aux[m*N+n]  (residual).
// EPI 3: split bf16 store: col<2048 -> Cout, else Cout2 (both ldc=2048).
// EPI 5: split-K partial: f32 store to Cout + blockIdx.z*NROWS*N, A/B advanced by z*K.
template <int EPI>
__global__ __launch_bounds__(256) void mfma_gemm(const bf16* __restrict__ A, int lda,
                                                 const bf16* __restrict__ B, int ldb,
                                                 void* __restrict__ Cout,
                                                 void* __restrict__ Cout2,
                                                 const float* __restrict__ aux,
                                                 int N, int K) {
    __shared__ __align__(16) bf16 sA[2][128 * 32];
    __shared__ __align__(16) bf16 sB[2][128 * 32];
    const int tid = threadIdx.x;
    const int w = tid >> 6;
    const int lane = tid & 63;
    const int quad = lane >> 4;
    const int l15 = lane & 15;
    const int m0 = blockIdx.x * 128;
    const int n0 = blockIdx.y * 128;
    const int wm = (w >> 1) * 64;
    const int wn = (w & 1) * 64;

    if constexpr (EPI == 5) {   // split-K: this block handles K-half blockIdx.z
        const int koff = blockIdx.z * K;
        A += koff;
        B += koff;
    }

    f32x4 acc[4][4];
    #pragma unroll
    for (int i = 0; i < 4; ++i)
        #pragma unroll
        for (int j = 0; j < 4; ++j)
            acc[i][j] = (f32x4){0.f, 0.f, 0.f, 0.f};

    const int sm = tid >> 2;
    const int q = (tid & 3) ^ ((sm >> 1) & 3);
    const bf16* gA0 = A + (size_t)(m0 + sm) * lda + q * 8;
    const bf16* gA1 = gA0 + (size_t)64 * lda;
    const bf16* gB0 = B + (size_t)(n0 + sm) * ldb + q * 8;
    const bf16* gB1 = gB0 + (size_t)64 * ldb;
    bf16* lA0c0 = sA[0] + w * 512;
    bf16* lA1c0 = sA[0] + 2048 + w * 512;
    bf16* lA0c1 = sA[1] + w * 512;
    bf16* lA1c1 = sA[1] + 2048 + w * 512;
    bf16* lB0c0 = sB[0] + w * 512;
    bf16* lB1c0 = sB[0] + 2048 + w * 512;
    bf16* lB0c1 = sB[1] + w * 512;
    bf16* lB1c1 = sB[1] + 2048 + w * 512;

    const int sw2 = (l15 >> 1) & 3;
    const int qx = (quad ^ sw2) * 8;

    for (int k0 = 0; k0 < K; k0 += 64) {
        gll16(gA0 + k0, lA0c0);
        gll16(gA1 + k0, lA1c0);
        gll16(gB0 + k0, lB0c0);
        gll16(gB1 + k0, lB1c0);
        gll16(gA0 + k0 + 32, lA0c1);
        gll16(gA1 + k0 + 32, lA1c1);
        gll16(gB0 + k0 + 32, lB0c1);
        gll16(gB1 + k0 + 32, lB1c1);
        __syncthreads();
        #pragma unroll
        for (int ch = 0; ch < 2; ++ch) {
            short8 af[4], bfr[4];
            #pragma unroll
            for (int f = 0; f < 4; ++f) {
                af[f]  = *reinterpret_cast<const short8*>(sA[ch] + (wm + f * 16 + l15) * 32 + qx);
                bfr[f] = *reinterpret_cast<const short8*>(sB[ch] + (wn + f * 16 + l15) * 32 + qx);
            }
            #pragma unroll
            for (int i = 0; i < 4; ++i)
                #pragma unroll
                for (int j = 0; j < 4; ++j)
                    acc[i][j] = __builtin_amdgcn_mfma_f32_16x16x32_bf16(af[i], bfr[j], acc[i][j], 0, 0, 0);
        }
        __syncthreads();
    }

    // epilogue: C/D layout col = lane&15, row = quad*4 + reg  [verified m89/m91]
    const int rbase = m0 + wm + quad * 4;
    if constexpr (EPI == 1) {
        bf16* C = (bf16*)Cout;
        #pragma unroll
        for (int i = 0; i < 4; ++i)
            #pragma unroll
            for (int r = 0; r < 4; ++r) {
                const size_t ro = (size_t)(rbase + i * 16 + r) * N;
                #pragma unroll
                for (int j = 0; j < 4; ++j) {
                    const int c = n0 + wn + j * 16 + l15;
                    float v = acc[i][j][r] + aux[c];
                    if (v < 15.f) v = __logf(1.f + __expf(v));   // softplus (fast, err ~1e-6)
                    C[ro + c] = f2b(v);
                }
            }
    } else if constexpr (EPI == 2) {
        float* C = (float*)Cout;
        #pragma unroll
        for (int i = 0; i < 4; ++i)
            #pragma unroll
            for (int r = 0; r < 4; ++r) {
                const size_t ro = (size_t)(rbase + i * 16 + r) * N;
                #pragma unroll
                for (int j = 0; j < 4; ++j) {
                    const int c = n0 + wn + j * 16 + l15;
                    C[ro + c] = acc[i][j][r] + aux[ro + c];
                }
            }
    } else if constexpr (EPI == 3) {
        bf16* C = (bf16*)((n0 < 2048) ? Cout : Cout2);
        const int cb = (n0 & 2047) + wn;
        #pragma unroll
        for (int i = 0; i < 4; ++i)
            #pragma unroll
            for (int r = 0; r < 4; ++r) {
                const size_t ro = (size_t)(rbase + i * 16 + r) * 2048;
                #pragma unroll
                for (int j = 0; j < 4; ++j)
                    C[ro + cb + j * 16 + l15] = f2b(acc[i][j][r]);
            }
    } else {  // EPI == 5: f32 partial store (split-K)
        float* C = (float*)Cout + (size_t)blockIdx.z * NROWS * N;
        #pragma unroll
        for (int i = 0; i < 4; ++i)
            #pragma unroll
            for (int r = 0; r < 4; ++r) {
                const size_t ro = (size_t)(rbase + i * 16 + r) * N;
                #pragma unroll
                for (int j = 0; j < 4; ++j)
                    C[ro + n0 + wn + j * 16 + l15] = acc[i][j][r];
            }
    }
}

// ---------------- x_proj split-K combine: p0+p1 -> dtr (bf16) + bcbuf (f32) ----------------
__global__ __launch_bounds__(256) void combine_xproj(const float* __restrict__ p0,
                                                     const float* __restrict__ p1,
                                                     bf16* __restrict__ dtr,
                                                     float* __restrict__ bcbuf) {
    const int idx = blockIdx.x * 256 + threadIdx.x;   // over NROWS*128
    const int c = idx & 127;
    const int row = idx >> 7;
    const float v = p0[idx] + p1[idx];
    if (c < 64) dtr[(size_t)row * 64 + c] = f2b(v);
    else if (c < 96) bcbuf[(size_t)row * 32 + (c - 64)] = v;
}

// ============== chunked selective scan (3 passes), NC = chunk count ==============
// bcbuf: [row][32] f32 — B at +0, C at +16 — block-uniform per (b,c): staged in LDS once.
// exp-trick: S4D init gives a[s] = a[0]*(s+1), so exp(dtv*a[s]) = e1^(s+1), e1=exp(dtv*a[0]).
// Checked per thread against actual A_log; generic fallback keeps correctness input-independent.
__device__ __forceinline__ bool pow_ok(const float* a) {
    bool ok = true;
    #pragma unroll
    for (int s = 1; s < 16; ++s) {
        const float t = a[0] * (s + 1);
        ok = ok && (fabsf(a[s] - t) <= 1e-4f * fabsf(t) + 1e-6f);
    }
    return ok;
}

template <int NC>
__global__ __launch_bounds__(256) void scan_passA(const bf16* __restrict__ dt,
                                                  const bf16* __restrict__ xc,
                                                  const float* __restrict__ bcbuf,
                                                  const float* __restrict__ A_log,
                                                  float* __restrict__ hend,
                                                  float* __restrict__ sumdt) {
    constexpr int LC = SEQ_N / NC;
    __shared__ __align__(16) float sbc[LC * 32];
    const int e = blockIdx.x * 256 + threadIdx.x;
    const int c = blockIdx.y;
    const int b = blockIdx.z;
    const size_t rbase = (size_t)b * SEQ_N + (size_t)c * LC;
    // stage this chunk's B rows (and C, contiguous) into LDS
    #pragma unroll
    for (int idx = threadIdx.x; idx < LC * 8; idx += 256)
        reinterpret_cast<float4*>(sbc)[idx] =
            reinterpret_cast<const float4*>(bcbuf + rbase * 32)[idx];
    float a[16], h[16];
    #pragma unroll
    for (int s = 0; s < 16; ++s) {
        a[s] = -__expf(A_log[e * 16 + s]);
        h[s] = 0.f;
    }
    const bool pw = pow_ok(a);
    float sd = 0.f;
    __syncthreads();
    for (int i = 0; i < LC; ++i) {
        const size_t row = rbase + i;
        const float dtv = b2f(dt[row * DINNER + e]);
        const float xv = b2f(xc[row * DINNER + e]);
        const float cdx = dtv * xv;
        const float4* bp = reinterpret_cast<const float4*>(sbc + i * 32);
        float Bv[16];
        *reinterpret_cast<float4*>(&Bv[0])  = bp[0];
        *reinterpret_cast<float4*>(&Bv[4])  = bp[1];
        *reinterpret_cast<float4*>(&Bv[8])  = bp[2];
        *reinterpret_cast<float4*>(&Bv[12]) = bp[3];
        sd += dtv;
        if (pw) {
            const float e1 = __expf(dtv * a[0]);
            float dAp = 1.f;
            #pragma unroll
            for (int s = 0; s < 16; ++s) {
                dAp *= e1;
                h[s] = fmaf(h[s], dAp, cdx * Bv[s]);
            }
        } else {
            #pragma unroll
            for (int s = 0; s < 16; ++s) {
                const float dA = __expf(dtv * a[s]);
                h[s] = fmaf(h[s], dA, cdx * Bv[s]);
            }
        }
    }
    const size_t o = ((size_t)b * NC + c) * DINNER + e;
    #pragma unroll
    for (int s = 0; s < 16; s += 4) {
        float4 v = {h[s], h[s + 1], h[s + 2], h[s + 3]};
        *reinterpret_cast<float4*>(hend + o * 16 + s) = v;
    }
    sumdt[o] = sd;
}

template <int NC>
__global__ __launch_bounds__(256) void scan_passB(float* hstate,
                                                  const float* __restrict__ sumdt,
                                                  const float* __restrict__ A_log) {
    const int g = blockIdx.x * 256 + threadIdx.x;
    const int s = g & 15;
    const int e = (g >> 4) & (DINNER - 1);
    const int b = g >> 15;
    const float a = -__expf(A_log[e * 16 + s]);
    float H = 0.f;
    for (int c = 0; c < NC; ++c) {
        const size_t o = ((size_t)b * NC + c) * DINNER + e;
        const float he = hstate[o * 16 + s];
        const float sd = sumdt[o];
        hstate[o * 16 + s] = H;
        H = fmaf(H, __expf(a * sd), he);
    }
}

template <int NC>
__global__ __launch_bounds__(256) void scan_passC(const bf16* dt,
                                                  const bf16* __restrict__ xc,
                                                  const bf16* __restrict__ z,
                                                  const float* __restrict__ bcbuf,
                                                  const float* __restrict__ A_log,
                                                  const float* __restrict__ D_skip,
                                                  const float* __restrict__ hinit,
                                                  bf16* y) {
    constexpr int LC = SEQ_N / NC;
    __shared__ __align__(16) float sbc[LC * 32];
    const int e = blockIdx.x * 256 + threadIdx.x;
    const int c = blockIdx.y;
    const int b = blockIdx.z;
    const size_t rbase = (size_t)b * SEQ_N + (size_t)c * LC;
    #pragma unroll
    for (int idx = threadIdx.x; idx < LC * 8; idx += 256)
        reinterpret_cast<float4*>(sbc)[idx] =
            reinterpret_cast<const float4*>(bcbuf + rbase * 32)[idx];
    float a[16], h[16];
    #pragma unroll
    for (int s = 0; s < 16; ++s) a[s] = -__expf(A_log[e * 16 + s]);
    const bool pw = pow_ok(a);
    const float dsk = D_skip[e];
    const size_t o = ((size_t)b * NC + c) * DINNER + e;
    #pragma unroll
    for (int s = 0; s < 16; s += 4) {
        float4 v = *reinterpret_cast<const float4*>(hinit + o * 16 + s);
        h[s] = v.x; h[s + 1] = v.y; h[s + 2] = v.z; h[s + 3] = v.w;
    }
    __syncthreads();
    for (int i = 0; i < LC; ++i) {
        const size_t row = rbase + i;
        const float dtv = b2f(dt[row * DINNER + e]);
        const float xv = b2f(xc[row * DINNER + e]);
        const float zv = b2f(z[row * DINNER + e]);
        const float cdx = dtv * xv;
        const float4* bp = reinterpret_cast<const float4*>(sbc + i * 32);
        float Bv[16], Cv[16];
        *reinterpret_cast<float4*>(&Bv[0])  = bp[0];
        *reinterpret_cast<float4*>(&Bv[4])  = bp[1];
        *reinterpret_cast<float4*>(&Bv[8])  = bp[2];
        *reinterpret_cast<float4*>(&Bv[12]) = bp[3];
        *reinterpret_cast<float4*>(&Cv[0])  = bp[4];
        *reinterpret_cast<float4*>(&Cv[4])  = bp[5];
        *reinterpret_cast<float4*>(&Cv[8])  = bp[6];
        *reinterpret_cast<float4*>(&Cv[12]) = bp[7];
        float yv = 0.f;
        if (pw) {
            const float e1 = __expf(dtv * a[0]);
            float dAp = 1.f;
            #pragma unroll
            for (int s = 0; s < 16; ++s) {
                dAp *= e1;
                h[s] = fmaf(h[s], dAp, cdx * Bv[s]);
                yv = fmaf(h[s], Cv[s], yv);
            }
        } else {
            #pragma unroll
            for (int s = 0; s < 16; ++s) {
                const float dA = __expf(dtv * a[s]);
                h[s] = fmaf(h[s], dA, cdx * Bv[s]);
                yv = fmaf(h[s], Cv[s], yv);
            }
        }
        const float g = (yv + dsk * xv) * (zv / (1.f + __expf(-zv)));
        y[row * DINNER + e] = f2b(g);
    }
}

extern "C" void kernel_launch(void* const* d_in, const int* in_sizes, int n_in,
                              void* d_out, int out_size, void* d_ws, size_t ws_size,
                              hipStream_t stream) {
    const float* x         = (const float*)d_in[0];
    const float* in_proj_w = (const float*)d_in[1];
    const float* conv_w    = (const float*)d_in[2];
    const float* conv_b    = (const float*)d_in[3];
    const float* x_proj_w  = (const float*)d_in[4];
    const float* dt_proj_w = (const float*)d_in[5];
    const float* dt_proj_b = (const float*)d_in[6];
    const float* A_log     = (const float*)d_in[7];
    const float* D_skip    = (const float*)d_in[8];
    const float* out_proj_w= (const float*)d_in[9];
    float* out = (float*)d_out;

    // workspace layout (bytes)
    char* ws = (char*)d_ws;
    bf16*  xcraw = (bf16*)(ws + 0);            // 67,108,864  [-> dtb -> y]
    bf16*  xc    = (bf16*)(ws + 67108864);     // 67,108,864  [u lives here first]
    bf16*  dtr   = (bf16*)(ws + 134217728);    //  2,097,152  [16384 x 64 bf16]
    float* bcbuf = (float*)(ws + 136314880);   //  2,097,152  [16384 x 32 f32]
    bf16*  w_in  = (bf16*)(ws + 140509184);    //  8,388,608
    bf16*  w_xp  = (bf16*)(ws + 148897792);    //    524,288  [padded to 128 x 2048]
    bf16*  w_dt  = (bf16*)(ws + 149422080);    //    262,144
    bf16*  w_out = (bf16*)(ws + 149684224);    //  4,194,304
    float* hend  = (float*)(ws + 153878528);   // NC=64: 33,554,432 | NC=32: 16,777,216
    bf16*  u     = xc;
    bf16*  dtb   = xcraw;
    bf16*  yb    = dtb;
    bf16*  zbuf  = (bf16*)d_out;               // z in d_out; overwritten by out-proj last
    // x_proj split-K partials alias hend (dead until scanA): 2 x 8 MB f32
    float* xp_p0 = hend;
    float* xp_p1 = hend + (size_t)NROWS * 128;

    const bool big = (ws_size >= 189530112ULL);   // room for NC=64 layout?
    float* sumdt = (float*)(ws + (big ? 187432960 : 170655744));

    // 0+1. weight converts + rmsnorm (single launch)
    prep_kernel<<<NROWS + CVT_TOTAL / 256, 256, 0, stream>>>(
        x, u, in_proj_w, w_in, x_proj_w, w_xp, dt_proj_w, w_dt, out_proj_w, w_out);
    // 2. xz = u @ in_proj^T, split-stored: cols [0,2048)->xcraw, [2048,4096)->zbuf
    mfma_gemm<3><<<dim3(NROWS / 128, 4096 / 128), 256, 0, stream>>>(
        u, DMODEL, w_in, DMODEL, xcraw, zbuf, nullptr, 4096, DMODEL);
    // 3. conv + silu -> xc (overwrites u; reads only xcraw)
    conv_silu4_kernel<<<(NROWS * DINNER) / 1024, 256, 0, stream>>>(xcraw, conv_w, conv_b, xc);
    // 4. x_proj split-K=2: partials (f32, N=128) -> combine into dtr + bcbuf
    mfma_gemm<5><<<dim3(NROWS / 128, 1, 2), 256, 0, stream>>>(
        xc, DINNER, w_xp, DINNER, xp_p0, nullptr, nullptr, 128, DINNER / 2);
    combine_xproj<<<(NROWS * 128) / 256, 256, 0, stream>>>(xp_p0, xp_p1, dtr, bcbuf);
    // 5. dt = softplus(dtr @ dt_proj^T + b)  [16384, 2048]  (over xcraw)
    mfma_gemm<1><<<dim3(NROWS / 128, DINNER / 128), 256, 0, stream>>>(
        dtr, DTRANK, w_dt, DTRANK, dtb, nullptr, dt_proj_b, DINNER, DTRANK);
    // 6. chunked selective scan (NC chosen by available workspace; constant per harness)
    if (big) {
        scan_passA<64><<<dim3(DINNER / 256, 64, BATCH_N), 256, 0, stream>>>(
            dtb, xc, bcbuf, A_log, hend, sumdt);
        scan_passB<64><<<(BATCH_N * DINNER * DSTATE) / 256, 256, 0, stream>>>(hend, sumdt, A_log);
        scan_passC<64><<<dim3(DINNER / 256, 64, BATCH_N), 256, 0, stream>>>(
            dtb, xc, zbuf, bcbuf, A_log, D_skip, hend, yb);
    } else {
        scan_passA<32><<<dim3(DINNER / 256, 32, BATCH_N), 256, 0, stream>>>(
            dtb, xc, bcbuf, A_log, hend, sumdt);
        scan_passB<32><<<(BATCH_N * DINNER * DSTATE) / 256, 256, 0, stream>>>(hend, sumdt, A_log);
        scan_passC<32><<<dim3(DINNER / 256, 32, BATCH_N), 256, 0, stream>>>(
            dtb, xc, zbuf, bcbuf, A_log, D_skip, hend, yb);
    }
    // 7. out = x + y @ out_proj^T  [16384, 1024]
    mfma_gemm<2><<<dim3(NROWS / 128, DMODEL / 128), 256, 0, stream>>>(
        yb, DINNER, w_out, DINNER, out, nullptr, x, DMODEL, DINNER);
    (void)in_sizes; (void)n_in; (void)out_size;
}